// Round 12
// baseline (883.496 us; speedup 1.0000x reference)
//
#include <hip/hip_runtime.h>
#include <hip/hip_bf16.h>

typedef unsigned short ushortt;
typedef __attribute__((ext_vector_type(8))) short short8v;
typedef __attribute__((ext_vector_type(4))) float f32x4;

#define H_ 32
#define W_ 32
#define C_ 3
#define PH_ 5
#define PW_ 5
#define HP_ 28
#define WP_ 28
#define P_ 784
#define N_ 32
#define L_ 75
#define LP_ 80            /* padded L for float4 staging */
#define G_ 2
#define M_ 384
#define MM_ (M_*M_)       /* 147456 */
#define PN_ (P_*N_)       /* 25088 */
#define JITTER_ 1e-6
#define PNB_ 3136         /* patchnorm blocks: PN_/8 */
#define P1B_ 113          /* prep1 blocks: ceil(G_*L_*M_/512) */

__device__ __forceinline__ float bf2f(ushortt u) {
  return __uint_as_float(((unsigned int)u) << 16);
}
__device__ __forceinline__ ushortt f2bf(float f) {
  __hip_bfloat16 h = __float2bfloat16(f);
  ushortt u;
  __builtin_memcpy(&u, &h, sizeof(u));
  return u;
}

// accurate exp(t) for t <= 0, fp64
__device__ __forceinline__ double exp64(double t) {
  double y = t * 1.4426950408889634;
  double nn = rint(y);
  double z = (y - nn) * 0.6931471805599453;
  double e = 1.6059043836821613e-10;
  e = fma(e, z, 2.08767569878681e-9);
  e = fma(e, z, 2.505210838544172e-8);
  e = fma(e, z, 2.755731922398589e-7);
  e = fma(e, z, 2.7557319223985893e-6);
  e = fma(e, z, 2.48015873015873e-5);
  e = fma(e, z, 1.984126984126984e-4);
  e = fma(e, z, 1.3888888888888889e-3);
  e = fma(e, z, 8.333333333333333e-3);
  e = fma(e, z, 4.1666666666666664e-2);
  e = fma(e, z, 1.6666666666666666e-1);
  e = fma(e, z, 0.5);
  e = fma(e, z, 1.0);
  e = fma(e, z, 1.0);
  return ldexp(e, (int)nn);
}

// ================= merged prep: patchnorm (blocks 0..PNB_-1),
//                   Zt/znorm/out-init (next P1B_), Kuu tiles (last 288) ======
__global__ __launch_bounds__(512) void k_prep(
    const float* __restrict__ xin, const float* __restrict__ Z,
    const float* vptr, const float* lptr,
    float* __restrict__ Zt, float* __restrict__ znorm,
    float* __restrict__ outp, float* __restrict__ pat,
    float* __restrict__ pnorm,
    double* __restrict__ Kuu64, float* __restrict__ Kuu32) {
  int b = blockIdx.x;
  if (b < PNB_) {
    // ---- patchnorm: 8 waves/block, one wave per x ----
    int wv = threadIdx.x >> 6;
    int t = threadIdx.x & 63;
    int x = b * 8 + wv;
    int n = x & 31, p = x >> 5;
    int hp = p / WP_, wp = p % WP_;
    const float* xb = xin + n * (H_ * W_ * C_);
    auto pval = [&](int l) -> float {
      if (l >= L_) return 0.f;
      int q = l / C_, c = l % C_;
      int i = q / PW_, j = q % PW_;
      return xb[((hp + i) * W_ + (wp + j)) * C_ + c];
    };
    float v1 = pval(t);
    float v2 = (t < 16) ? pval(t + 64) : 0.f;
    pat[(size_t)x * LP_ + t] = v1;
    if (t < 16) pat[(size_t)x * LP_ + 64 + t] = v2;
    float s = v1 * v1 + v2 * v2;
#pragma unroll
    for (int off = 32; off; off >>= 1) s += __shfl_down(s, off);
    if (t == 0) pnorm[x] = s;
    return;
  }
  if (b < PNB_ + P1B_) {
    // ---- Zt transpose + znorm + output init ----
    int idx = (b - PNB_) * 512 + threadIdx.x;
    if (idx < G_ * L_ * M_) {
      int m = idx % M_;
      int l = (idx / M_) % L_;
      int g = idx / (M_ * L_);
      Zt[idx] = Z[(g * M_ + m) * L_ + l];
    }
    if (idx < G_ * M_) {
      const float* zr = Z + (size_t)idx * L_;
      float s = 0.f;
      for (int l = 0; l < L_; ++l) s = fmaf(zr[l], zr[l], s);
      znorm[idx] = s;
    }
    if (idx < PN_ * G_) {
      outp[idx] = 0.f;
      outp[PN_ * G_ + idx] = vptr[0];
    }
    return;
  }
  // ---- Kuu fp64 + fp32 copy: tiled, 32x32 per block ----
  int q = b - PNB_ - P1B_;
  int bx = q % 12, by = (q / 12) % 12, g = q / 144;
  int row0 = by * 32, col0 = bx * 32;
  __shared__ float Zr[32][76], Zc[32][76];
  int t = threadIdx.x;
  for (int idx = t; idx < 2400; idx += 512) {
    int r = idx / 75, l = idx % 75;
    Zr[r][l] = Z[((size_t)(g * M_ + row0 + r)) * L_ + l];
    Zc[r][l] = Z[((size_t)(g * M_ + col0 + r)) * L_ + l];
  }
  __syncthreads();

  int ty = t >> 4, tx = t & 15;
  double s0 = 0.0, s1 = 0.0;
#pragma unroll 5
  for (int l = 0; l < 75; ++l) {
    double zi = (double)Zr[ty][l];
    double d0 = zi - (double)Zc[tx][l];
    double d1 = zi - (double)Zc[tx + 16][l];
    s0 = fma(d0, d0, s0);
    s1 = fma(d1, d1, s1);
  }
  double v = (double)vptr[0], ls = (double)lptr[0];
  double inv2 = -0.5 / (ls * ls);
  int r = row0 + ty;
  double ss[2] = {s0, s1};
#pragma unroll
  for (int cc = 0; cc < 2; ++cc) {
    int j = col0 + tx + cc * 16;
    double val = v * exp64(ss[cc] * inv2);
    if (r == j) val += JITTER_;
    size_t o = (size_t)g * MM_ + (size_t)r * M_ + j;
    Kuu64[o] = val;
    Kuu32[o] = (float)val;
  }
}

// ================= fused: 192x192 blocked GJ inverse (blocks 0..1) =================
// ================= + Kuf-build tiles (blocks 2..)                  =================
// r8-verified structure (measured 104-105us/dispatch): Pinv via LDS,
// single-wave phase 2. (r9's all-wave redundant shuffle inversion regressed
// to 145us: __shfl = ds_bpermute = LDS pipe; 16x traffic.)
__global__ __launch_bounds__(1024, 1) void k_invkufg(
    const float* __restrict__ Ain, float* __restrict__ Aout,
    const float* __restrict__ pat, const float* __restrict__ Zt,
    const float* __restrict__ znorm, const float* __restrict__ pnorm,
    const float* vptr, const float* lptr,
    float* __restrict__ Kx, ushortt* __restrict__ Khi, ushortt* __restrict__ Klo,
    int x0, int chx, int tile0) {
  __shared__ __align__(16) char smem[37888];

  if (blockIdx.x < G_) {
    // ---------------- inversion path ----------------
    __builtin_amdgcn_s_setprio(1);
    float (*rowb)[192]  = (float(*)[192])(smem);           // pivot-row panel R
    float (*rowb2)[192] = (float(*)[192])(smem + 12288);   // R' = Pinv * R
    float (*colbT)[192] = (float(*)[192])(smem + 24576);   // colbT[k][i]
    float (*Pinv)[16]   = (float(*)[16])(smem + 36864);

    int g = blockIdx.x;
    const float* A = Ain + (size_t)g * MM_;
    float* O = Aout + (size_t)g * MM_;
    int t = threadIdx.x;
    int rid = t >> 5, cid = t & 31;
    int r0 = rid * 6, c0 = cid * 6;

    float a[6][6];
#pragma unroll
    for (int ii = 0; ii < 6; ++ii) {
#pragma unroll
      for (int j2 = 0; j2 < 3; ++j2) {
        float2 v = *(const float2*)&A[(size_t)(r0 + ii) * M_ + c0 + j2 * 2];
        a[ii][j2 * 2 + 0] = v.x; a[ii][j2 * 2 + 1] = v.y;
      }
    }

    for (int bs = 0; bs < 12; ++bs) {
      int kp = bs * 16;
      // ---- phase 1: publish panels from registers ----
#pragma unroll
      for (int ii = 0; ii < 6; ++ii) {
        int k = r0 + ii - kp;
        if ((unsigned)k < 16u) {
#pragma unroll
          for (int jj = 0; jj < 6; ++jj) rowb[k][c0 + jj] = a[ii][jj];
        }
      }
#pragma unroll
      for (int jj = 0; jj < 6; ++jj) {
        int c = c0 + jj - kp;
        if ((unsigned)c < 16u) {
#pragma unroll
          for (int ii = 0; ii < 6; ++ii) colbT[c][r0 + ii] = a[ii][jj];
        }
      }
      __syncthreads();

      // ---- phase 2: wave 0 inverts 16x16 pivot block in registers ----
      if (t < 64) {
        int r = t >> 2, cg = t & 3;
        float vals[4];
#pragma unroll
        for (int j = 0; j < 4; ++j) vals[j] = rowb[r][kp + cg * 4 + j];
#pragma unroll
        for (int k = 0; k < 16; ++k) {
          const int cgk = k >> 2, jk = k & 3;
          float pkk = __shfl(vals[jk], k * 4 + cgk);
          float c_ = __shfl(vals[jk], (t & 0x3c) | cgk);
          float p = 1.0f / pkk;
          float cp = c_ * p;
          bool pivRow = (r == k);
#pragma unroll
          for (int j = 0; j < 4; ++j) {
            float prj = __shfl(vals[j], k * 4 + cg);
            bool pivCol = (cg == cgk) && (j == jk);
            float gen = fmaf(-cp, prj, vals[j]);
            float nv = pivRow ? (pivCol ? p : p * prj)
                              : (pivCol ? -cp : gen);
            vals[j] = nv;
          }
        }
#pragma unroll
        for (int j = 0; j < 4; ++j) Pinv[r][cg * 4 + j] = vals[j];
      }
      __syncthreads();

      // ---- phase 3: rowb2 <- Pinv * rowb, all 1024 threads ----
      {
        int r = t >> 6;
        float pv[16];
#pragma unroll
        for (int m = 0; m < 16; ++m) pv[m] = Pinv[r][m];
#pragma unroll
        for (int rep = 0; rep < 3; ++rep) {
          int c = (t & 63) + 64 * rep;
          int cc = c - kp;
          float s;
          if ((unsigned)cc < 16u) {
            s = pv[cc];
          } else {
            s = 0.f;
#pragma unroll
            for (int m = 0; m < 16; ++m) s = fmaf(pv[m], rowb[m][c], s);
          }
          rowb2[r][c] = s;
        }
      }
      __syncthreads();

      // ---- phase 4: rank-16 update (bounded unroll: no spill) ----
#pragma unroll
      for (int jj = 0; jj < 6; ++jj) {
        int c = c0 + jj - kp;
        if ((unsigned)c < 16u) {
#pragma unroll
          for (int ii = 0; ii < 6; ++ii) a[ii][jj] = 0.f;
        }
      }
#pragma unroll 2
      for (int k = 0; k < 16; ++k) {
        float rk[6], ck[6];
#pragma unroll
        for (int j2 = 0; j2 < 3; ++j2) {
          float2 v = *(const float2*)&rowb2[k][c0 + j2 * 2];
          rk[j2 * 2 + 0] = v.x; rk[j2 * 2 + 1] = v.y;
        }
#pragma unroll
        for (int i2 = 0; i2 < 3; ++i2) {
          float2 v = *(const float2*)&colbT[k][r0 + i2 * 2];
          ck[i2 * 2 + 0] = v.x; ck[i2 * 2 + 1] = v.y;
        }
#pragma unroll
        for (int ii = 0; ii < 6; ++ii)
#pragma unroll
          for (int jj = 0; jj < 6; ++jj)
            a[ii][jj] = fmaf(-ck[ii], rk[jj], a[ii][jj]);
      }
      // pivot rows: overwrite with R'
#pragma unroll
      for (int ii = 0; ii < 6; ++ii) {
        int k = r0 + ii - kp;
        if ((unsigned)k < 16u) {
#pragma unroll
          for (int jj = 0; jj < 6; ++jj) a[ii][jj] = rowb2[k][c0 + jj];
        }
      }
      __syncthreads();
    }

#pragma unroll
    for (int ii = 0; ii < 6; ++ii) {
#pragma unroll
      for (int j2 = 0; j2 < 3; ++j2) {
        float2 v = {a[ii][j2 * 2 + 0], a[ii][j2 * 2 + 1]};
        *(float2*)&O[(size_t)(r0 + ii) * M_ + c0 + j2 * 2] = v;
      }
    }
    return;
  }

  // ---------------- kufg path: 4 groups x one 64x64 tile ----------------
  typedef float lds68[16][68];
  lds68* As = (lds68*)(smem);            // As[grp][k][r]
  lds68* Bs = (lds68*)(smem + 17408);    // Bs[grp][k][c]

  int bid = (int)blockIdx.x - G_;
  int grp = threadIdx.x >> 8;
  int t = threadIdx.x & 255;
  int tile = tile0 + bid * 4 + grp;
  int chx64 = chx >> 6;
  int col = tile % 6;
  int rg = tile / 6;
  int g = rg / chx64;
  int row = rg % chx64;
  int col0 = col * 64;
  int row0 = row * 64;
  int tr = t >> 4, tc = t & 15;
  float acc[4][4] = {};

  for (int kt = 0; kt < LP_; kt += 16) {
    {
      int r = t >> 2, k4 = (t & 3) * 4;
      float4 av = *(const float4*)&pat[(size_t)(x0 + row0 + r) * LP_ + kt + k4];
      As[grp][k4 + 0][r] = av.x;
      As[grp][k4 + 1][r] = av.y;
      As[grp][k4 + 2][r] = av.z;
      As[grp][k4 + 3][r] = av.w;
    }
    {
      int k = t >> 4, c4 = (t & 15) * 4;
      float4 bv = {0.f, 0.f, 0.f, 0.f};
      if (kt + k < L_)
        bv = *(const float4*)&Zt[((size_t)(g * L_ + kt + k)) * M_ + col0 + c4];
      *(float4*)&Bs[grp][k][c4] = bv;
    }
    __syncthreads();
#pragma unroll 4
    for (int k = 0; k < 16; ++k) {
      float4 av = *(const float4*)&As[grp][k][tr * 4];
      float4 bv = *(const float4*)&Bs[grp][k][tc * 4];
      float a4[4] = {av.x, av.y, av.z, av.w};
      float b4[4] = {bv.x, bv.y, bv.z, bv.w};
#pragma unroll
      for (int i = 0; i < 4; ++i)
#pragma unroll
        for (int j = 0; j < 4; ++j) acc[i][j] = fmaf(a4[i], b4[j], acc[i][j]);
    }
    __syncthreads();
  }
  float v = vptr[0], ls = lptr[0];
  float c2 = -0.72134752044f / (ls * ls);
#pragma unroll
  for (int i = 0; i < 4; ++i) {
    int xl = row0 + tr * 4 + i;
    float pn = pnorm[x0 + xl];
    float tmp[4];
    ushortt hi[4], lo[4];
#pragma unroll
    for (int j = 0; j < 4; ++j) {
      int m = col0 + tc * 4 + j;
      float sq = znorm[g * M_ + m] + pn - 2.0f * acc[i][j];
      tmp[j] = v * exp2f(sq * c2);
      hi[j] = f2bf(tmp[j]);
      lo[j] = f2bf(tmp[j] - bf2f(hi[j]));
    }
    size_t base = ((size_t)g * chx + xl) * M_ + col0 + tc * 4;
    float4 ov = {tmp[0], tmp[1], tmp[2], tmp[3]};
    *(float4*)&Kx[base] = ov;
    *(ushort4*)&Khi[base] = make_ushort4(hi[0], hi[1], hi[2], hi[3]);
    *(ushort4*)&Klo[base] = make_ushort4(lo[0], lo[1], lo[2], lo[3]);
  }
}

// ---------------- fp32 tiled GEMM ----------------
__global__ __launch_bounds__(512) void k_sgemm(
    const float* __restrict__ A, int lda, int tA, int sAg,
    const float* __restrict__ B, int ldb, int tB, int btril, int sBg,
    const float* __restrict__ Cin, int sCing, float beta,
    float alpha, int addI,
    float* __restrict__ Cout, int ldc, int sCg,
    float* __restrict__ CoutT, int ldt, int sTg,
    ushortt* __restrict__ shiOut, ushortt* __restrict__ sloOut,
    int M, int N, int K) {
  int g = blockIdx.z;
  int row0 = blockIdx.y * 32, col0 = blockIdx.x * 32;
  if (shiOut && col0 > row0) return;   // symmetric output: lower tiles only
  A += (size_t)g * sAg;
  B += (size_t)g * sBg;
  if (Cin) Cin += (size_t)g * sCing;
  if (Cout) Cout += (size_t)g * sCg;
  if (CoutT) CoutT += (size_t)g * sTg;
  if (shiOut) { shiOut += (size_t)g * sCg; sloOut += (size_t)g * sCg; }

  __shared__ __align__(16) float As[32][34], Bs[32][34];
  int t = threadIdx.x;
  int tx = t & 15, ty = t >> 4;
  float acc0 = 0.f, acc1 = 0.f;

  int kt0 = btril ? (col0 & ~31) : 0;  // tiles fully above tril are exact zeros
  for (int kt = kt0; kt < K; kt += 32) {
    for (int idx = t; idx < 1024; idx += 512) {
      int rr = idx >> 5, cc = idx & 31;
      {
        int gr = row0 + rr, gk = kt + cc;
        As[rr][cc] = tA ? A[(size_t)gk * lda + gr] : A[(size_t)gr * lda + gk];
      }
      {
        int gk = kt + rr, gc = col0 + cc;
        float bv = tB ? B[(size_t)gc * ldb + gk] : B[(size_t)gk * ldb + gc];
        if (btril && gc > gk) bv = 0.f;
        Bs[rr][cc] = bv;
      }
    }
    __syncthreads();
#pragma unroll 8
    for (int kk = 0; kk < 32; ++kk) {
      float a0 = As[ty][kk];
      float2 b = *(const float2*)&Bs[kk][tx * 2];
      acc0 = fmaf(a0, b.x, acc0);
      acc1 = fmaf(a0, b.y, acc1);
    }
    __syncthreads();
  }
  float accs[2] = {acc0, acc1};
#pragma unroll
  for (int b2 = 0; b2 < 2; ++b2) {
    int gr = row0 + ty, gc = col0 + tx * 2 + b2;
    float val = alpha * accs[b2];
    if (addI && gr == gc) val += 1.0f;
    if (Cin) val += beta * Cin[(size_t)gr * ldc + gc];
    if (Cout) Cout[(size_t)gr * ldc + gc] = val;
    if (CoutT) CoutT[(size_t)gc * ldt + gr] = val;
    if (shiOut) {
      ushortt h = f2bf(val);
      shiOut[(size_t)gr * ldc + gc] = h;
      sloOut[(size_t)gr * ldc + gc] = f2bf(val - bf2f(h));
      // mirror: acc symmetric; use transposed Cin element for exactness
      float vm = alpha * accs[b2];
      if (Cin) vm += beta * Cin[(size_t)gc * ldc + gr];
      ushortt hm = f2bf(vm);
      shiOut[(size_t)gc * ldc + gr] = hm;
      sloOut[(size_t)gc * ldc + gr] = f2bf(vm - bf2f(hm));
    }
  }
}

// ---------------- mixed-precision fp64-accum GEMM (Newton residual only) ----------------
__global__ __launch_bounds__(512) void k_dgemmx(
    const void* __restrict__ Ap, int aF64, int lda, int tA, size_t sAg,
    const void* __restrict__ Bp, int bF64, int ldb, int tB, int btril, size_t sBg,
    const void* __restrict__ Cp, int cF64, size_t sCing, double beta,
    double alpha, int addI,
    double* __restrict__ Cout, int ldc, size_t sCg,
    float* __restrict__ f32out,
    ushortt* __restrict__ shiOut, ushortt* __restrict__ sloOut,
    int M, int N, int K) {
  int g = blockIdx.z;
  const double* A64 = (const double*)Ap + (size_t)g * sAg;
  const float* A32 = (const float*)Ap + (size_t)g * sAg;
  const double* B64 = (const double*)Bp + (size_t)g * sBg;
  const float* B32 = (const float*)Bp + (size_t)g * sBg;
  const double* C64 = Cp ? (const double*)Cp + (size_t)g * sCing : nullptr;
  const float* C32 = Cp ? (const float*)Cp + (size_t)g * sCing : nullptr;
  if (Cout) Cout += (size_t)g * sCg;
  if (f32out) f32out += (size_t)g * sCg;
  if (shiOut) shiOut += (size_t)g * sCg;
  if (sloOut) sloOut += (size_t)g * sCg;

  __shared__ __align__(16) double As[32][34], Bs[32][34];
  int t = threadIdx.x;
  int tx = t & 15, ty = t >> 4;
  int row0 = blockIdx.y * 32, col0 = blockIdx.x * 32;
  double acc0 = 0., acc1 = 0.;

  for (int kt = 0; kt < K; kt += 32) {
    for (int idx = t; idx < 1024; idx += 512) {
      int rr = idx >> 5, cc = idx & 31;
      {
        int gr = row0 + rr, gk = kt + cc;
        size_t ai = tA ? ((size_t)gk * lda + gr) : ((size_t)gr * lda + gk);
        As[rr][cc] = aF64 ? A64[ai] : (double)A32[ai];
      }
      {
        int gk = kt + rr, gc = col0 + cc;
        size_t bi = tB ? ((size_t)gc * ldb + gk) : ((size_t)gk * ldb + gc);
        double bv = bF64 ? B64[bi] : (double)B32[bi];
        if (btril && gc > gk) bv = 0.0;
        Bs[rr][cc] = bv;
      }
    }
    __syncthreads();
#pragma unroll 8
    for (int kk = 0; kk < 32; ++kk) {
      double a0 = As[ty][kk];
      double2 b = *(const double2*)&Bs[kk][tx * 2];
      acc0 = fma(a0, b.x, acc0);
      acc1 = fma(a0, b.y, acc1);
    }
    __syncthreads();
  }
  double accs[2] = {acc0, acc1};
#pragma unroll
  for (int b2 = 0; b2 < 2; ++b2) {
    int gr = row0 + ty, gc = col0 + tx * 2 + b2;
    double val = alpha * accs[b2];
    if (addI && gr == gc) val += 1.0;
    if (C64) {
      double cv = cF64 ? C64[(size_t)gr * ldc + gc] : (double)C32[(size_t)gr * ldc + gc];
      val += beta * cv;
    }
    if (Cout) Cout[(size_t)gr * ldc + gc] = val;
    if (f32out) f32out[(size_t)gr * ldc + gc] = (float)val;
    if (shiOut) {
      float sv = (float)val;
      ushortt h = f2bf(sv);
      shiOut[(size_t)gr * ldc + gc] = h;
      sloOut[(size_t)gr * ldc + gc] = f2bf(sv - bf2f(h));
    }
  }
}

// ---------------- c_g = X * q_mu[:,g]  (fp32 X, fp64 accum) ----------------
__global__ void k_cvec32(const float* __restrict__ X, const float* __restrict__ qmu,
                         float* __restrict__ cvec) {
  int idx = blockIdx.x * 256 + threadIdx.x;
  if (idx >= G_ * M_) return;
  int m = idx % M_, g = idx / M_;
  const float* row = X + (size_t)g * MM_ + (size_t)m * M_;
  double s = 0.0;
  for (int k = 0; k < M_; ++k) s = fma((double)row[k], (double)qmu[k * G_ + g], s);
  cvec[idx] = (float)s;
}

// ---------------- Kuf as GEMM (64x64 tile) -> Kx fp32 + Khi/Klo bf16 ----------------
// (standalone version, used for chunks >= 1 when nc > 1)
__global__ __launch_bounds__(256) void k_kufg(const float* __restrict__ pat,
                                              const float* __restrict__ Zt,
                                              const float* __restrict__ znorm,
                                              const float* __restrict__ pnorm,
                                              const float* vptr, const float* lptr,
                                              float* __restrict__ Kx,
                                              ushortt* __restrict__ Khi,
                                              ushortt* __restrict__ Klo,
                                              int x0, int chx) {
  int g = blockIdx.z;
  int col0 = blockIdx.x * 64;
  int row0 = blockIdx.y * 64;
  __shared__ __align__(16) float As[16][68];
  __shared__ __align__(16) float Bs[16][68];
  int t = threadIdx.x;
  int tr = t >> 4, tc = t & 15;
  float acc[4][4] = {};

  for (int kt = 0; kt < LP_; kt += 16) {
    {
      int r = t >> 2, k4 = (t & 3) * 4;
      float4 av = *(const float4*)&pat[(size_t)(x0 + row0 + r) * LP_ + kt + k4];
      As[k4 + 0][r] = av.x;
      As[k4 + 1][r] = av.y;
      As[k4 + 2][r] = av.z;
      As[k4 + 3][r] = av.w;
    }
    {
      int k = t >> 4, c4 = (t & 15) * 4;
      float4 bv = {0.f, 0.f, 0.f, 0.f};
      if (kt + k < L_)
        bv = *(const float4*)&Zt[((size_t)(g * L_ + kt + k)) * M_ + col0 + c4];
      *(float4*)&Bs[k][c4] = bv;
    }
    __syncthreads();
#pragma unroll
    for (int k = 0; k < 16; ++k) {
      float4 av = *(const float4*)&As[k][tr * 4];
      float4 bv = *(const float4*)&Bs[k][tc * 4];
      float a4[4] = {av.x, av.y, av.z, av.w};
      float b4[4] = {bv.x, bv.y, bv.z, bv.w};
#pragma unroll
      for (int i = 0; i < 4; ++i)
#pragma unroll
        for (int j = 0; j < 4; ++j) acc[i][j] = fmaf(a4[i], b4[j], acc[i][j]);
    }
    __syncthreads();
  }
  float v = vptr[0], ls = lptr[0];
  float c2 = -0.72134752044f / (ls * ls);
#pragma unroll
  for (int i = 0; i < 4; ++i) {
    int xl = row0 + tr * 4 + i;
    float pn = pnorm[x0 + xl];
    float tmp[4];
    ushortt hi[4], lo[4];
#pragma unroll
    for (int j = 0; j < 4; ++j) {
      int m = col0 + tc * 4 + j;
      float sq = znorm[g * M_ + m] + pn - 2.0f * acc[i][j];
      tmp[j] = v * exp2f(sq * c2);
      hi[j] = f2bf(tmp[j]);
      lo[j] = f2bf(tmp[j] - bf2f(hi[j]));
    }
    size_t base = ((size_t)g * chx + xl) * M_ + col0 + tc * 4;
    float4 ov = {tmp[0], tmp[1], tmp[2], tmp[3]};
    *(float4*)&Kx[base] = ov;
    *(ushort4*)&Khi[base] = make_ushort4(hi[0], hi[1], hi[2], hi[3]);
    *(ushort4*)&Klo[base] = make_ushort4(lo[0], lo[1], lo[2], lo[3]);
  }
}

// ---------------- LDS frag helper: 16B-aligned read -> short8v ----------------
__device__ __forceinline__ short8v lds_frag(const ushortt* p) {
  int4 v = *(const int4*)p;
  short8v r;
  __builtin_memcpy(&r, &v, 16);
  return r;
}

// ---------------- MFMA U-GEMM + fold, LDS-staged ----------------
// r11 rewrite: 64-row x FULL-384-col tiles (was 128x128 with 3 column-blocks).
// - K-panels (Khi/Klo) now read exactly once from HBM (was 3x: 231->77MB).
// - Fold covers all 384 cols in one block -> direct stores, no atomics.
// - S panels (1.2MB) stay L2-resident across row-blocks.
// Block 256 = 4 waves; wave w owns rows w*16..w*16+15; acc = 24 col-tiles.
// LDS: A 2x64x40x2B + B 2x384x40x2B + cs = ~73KB -> 2 blocks/CU.
#define STR_ 40
__global__ __launch_bounds__(256) void k_ufoldm(
    const ushortt* __restrict__ Khi, const ushortt* __restrict__ Klo,
    const float* __restrict__ Kx32,
    const ushortt* __restrict__ Shi, const ushortt* __restrict__ Slo,
    const float* __restrict__ cvec, const float* vptr,
    float* __restrict__ outp, int x0, int chx) {
  int g = blockIdx.z;
  int row0 = blockIdx.y * 64;
  const ushortt* Ahg = Khi + (size_t)g * chx * M_;
  const ushortt* Alg = Klo + (size_t)g * chx * M_;
  const float* A32 = Kx32 + (size_t)g * chx * M_;
  const ushortt* Bhg = Shi + (size_t)g * MM_;
  const ushortt* Blg = Slo + (size_t)g * MM_;

  __shared__ __align__(16) ushortt Ahs[64][STR_], Als[64][STR_];
  __shared__ __align__(16) ushortt Bhs[384][STR_], Bls[384][STR_];
  __shared__ float cs[384];

  int t = threadIdx.x;
  cs[t] = cvec[g * M_ + t];
  if (t < 128) cs[256 + t] = cvec[g * M_ + 256 + t];

  int w = t >> 6, lane = t & 63, n15 = lane & 15, q = lane >> 4;
  int q8 = q * 8;

  f32x4 acc[24];
#pragma unroll
  for (int ct = 0; ct < 24; ++ct) acc[ct] = (f32x4){0.f, 0.f, 0.f, 0.f};

  for (int kt = 0; kt < M_; kt += 32) {
    // stage A (64 rows x 32k, hi+lo): threads 0..127
    if (t < 128) {
      int sr = t >> 1, sk = (t & 1) * 16;
      size_t abase = (size_t)(row0 + sr) * M_ + kt + sk;
      uint4 a0 = *(const uint4*)&Ahg[abase];
      uint4 a1 = *(const uint4*)&Ahg[abase + 8];
      *(uint4*)&Ahs[sr][sk] = a0;
      *(uint4*)&Ahs[sr][sk + 8] = a1;
      uint4 b0 = *(const uint4*)&Alg[abase];
      uint4 b1 = *(const uint4*)&Alg[abase + 8];
      *(uint4*)&Als[sr][sk] = b0;
      *(uint4*)&Als[sr][sk + 8] = b1;
    }
    // stage B (384 rows x 32k, hi+lo): all threads, 3 reps
#pragma unroll
    for (int rep = 0; rep < 3; ++rep) {
      int sr = (t >> 1) + 128 * rep, sk = (t & 1) * 16;
      size_t bbase = (size_t)sr * M_ + kt + sk;
      uint4 c0 = *(const uint4*)&Bhg[bbase];
      uint4 c1 = *(const uint4*)&Bhg[bbase + 8];
      *(uint4*)&Bhs[sr][sk] = c0;
      *(uint4*)&Bhs[sr][sk + 8] = c1;
      uint4 d0 = *(const uint4*)&Blg[bbase];
      uint4 d1 = *(const uint4*)&Blg[bbase + 8];
      *(uint4*)&Bls[sr][sk] = d0;
      *(uint4*)&Bls[sr][sk + 8] = d1;
    }
    __syncthreads();

    short8v ahi = lds_frag(&Ahs[w * 16 + n15][q8]);
    short8v alo = lds_frag(&Als[w * 16 + n15][q8]);
#pragma unroll 8
    for (int ct = 0; ct < 24; ++ct) {
      short8v bhi = lds_frag(&Bhs[ct * 16 + n15][q8]);
      short8v blo = lds_frag(&Bls[ct * 16 + n15][q8]);
      acc[ct] = __builtin_amdgcn_mfma_f32_16x16x32_bf16(ahi, bhi, acc[ct], 0, 0, 0);
      acc[ct] = __builtin_amdgcn_mfma_f32_16x16x32_bf16(ahi, blo, acc[ct], 0, 0, 0);
      acc[ct] = __builtin_amdgcn_mfma_f32_16x16x32_bf16(alo, bhi, acc[ct], 0, 0, 0);
    }
    __syncthreads();
  }

  // fold: FULL 384 cols per row -> exact fp32 k, fp64 partials, direct store.
  float var0 = vptr[0];
#pragma unroll
  for (int reg = 0; reg < 4; ++reg) {
    int xr2 = row0 + w * 16 + q * 4 + reg;
    const float* arow = &A32[(size_t)xr2 * M_];
    double pv = 0.0, pm = 0.0;
#pragma unroll 8
    for (int ct = 0; ct < 24; ++ct) {
      int col = ct * 16 + n15;
      float kval = arow[col];
      pv += (double)kval * acc[ct][reg];
      pm += (double)kval * cs[col];
    }
#pragma unroll
    for (int mk = 1; mk < 16; mk <<= 1) {
      pv += __shfl_xor(pv, mk, 16);
      pm += __shfl_xor(pm, mk, 16);
    }
    if (n15 == 0) {
      int x = x0 + xr2;
      int p = x >> 5, n = x & 31;
      int oidx = n * (P_ * G_) + p * G_ + g;
      outp[oidx] = (float)pm;
      outp[PN_ * G_ + oidx] = var0 + (float)pv;
    }
  }
}

extern "C" void kernel_launch(void* const* d_in, const int* in_sizes, int n_in,
                              void* d_out, int out_size, void* d_ws, size_t ws_size,
                              hipStream_t stream) {
  (void)out_size;
  const float* xin = (const float*)d_in[0];
  const float* Z = (const float*)d_in[1];
  const float* qmu = (const float*)d_in[2];
  const float* qsqrt = (const float*)d_in[3];
  const float* vptr = (const float*)d_in[4];
  const float* lptr = (const float*)d_in[5];
  {
    int scalars = 0;
    for (int i = 0; i < n_in; ++i) {
      if (in_sizes[i] == N_ * H_ * W_ * C_) xin = (const float*)d_in[i];
      else if (in_sizes[i] == G_ * M_ * L_) Z = (const float*)d_in[i];
      else if (in_sizes[i] == M_ * G_) qmu = (const float*)d_in[i];
      else if (in_sizes[i] == G_ * MM_) qsqrt = (const float*)d_in[i];
      else if (in_sizes[i] == 1) {
        if (scalars == 0) vptr = (const float*)d_in[i];
        else lptr = (const float*)d_in[i];
        ++scalars;
      }
    }
  }
  float* outp = (float*)d_out;

  auto align256 = [](size_t b) { return (b + 255) & ~(size_t)255; };
  size_t fixed = 0;
  fixed += align256((size_t)G_ * L_ * M_ * 4);      // Zt
  fixed += align256((size_t)G_ * M_ * 4);           // znorm
  fixed += align256((size_t)PN_ * LP_ * 4);         // pat
  fixed += align256((size_t)PN_ * 4);               // pnorm
  fixed += align256((size_t)G_ * MM_ * 4) * 2;      // Kuu32, Kinv32
  fixed += align256((size_t)G_ * 192 * 192 * 4);    // Ebuf
  fixed += align256((size_t)G_ * MM_ * 8);          // Kuu64
  fixed += align256((size_t)G_ * MM_ * 4) * 2;      // Xf, Rf (fp32 since r7)
  fixed += align256((size_t)G_ * MM_ * 2) * 2;      // Shi, Slo
  fixed += align256((size_t)G_ * M_ * 4);           // cvec
  size_t kfam = (size_t)G_ * PN_ * M_ * 8;          // Kx fp32 + Khi + Klo per full span
  int nc = 4;
  if (ws_size >= fixed + align256(kfam) + (1u << 20)) nc = 1;
  else if (ws_size >= fixed + align256(kfam / 2) + (1u << 20)) nc = 2;
  int chx = PN_ / nc;   // divisible by 128 for nc in {1,2,4}

  char* w = (char*)d_ws;
  auto alloc = [&](size_t bytes) {
    char* r = w;
    w += (bytes + 255) & ~(size_t)255;
    return r;
  };
  float* Zt      = (float*)alloc((size_t)G_ * L_ * M_ * 4);
  float* znorm   = (float*)alloc((size_t)G_ * M_ * 4);
  float* pat     = (float*)alloc((size_t)PN_ * LP_ * 4);
  float* pnorm   = (float*)alloc((size_t)PN_ * 4);
  float* Kuu32   = (float*)alloc((size_t)G_ * MM_ * 4);
  float* Kinv32  = (float*)alloc((size_t)G_ * MM_ * 4);
  float* Ebuf    = (float*)alloc((size_t)G_ * 192 * 192 * 4);
  double* Kuu64  = (double*)alloc((size_t)G_ * MM_ * 8);
  float* Xf      = (float*)alloc((size_t)G_ * MM_ * 4);
  float* Rf      = (float*)alloc((size_t)G_ * MM_ * 4);
  ushortt* Shi   = (ushortt*)alloc((size_t)G_ * MM_ * 2);
  ushortt* Slo   = (ushortt*)alloc((size_t)G_ * MM_ * 2);
  float* cvec    = (float*)alloc((size_t)G_ * M_ * 4);
  float* Kx      = (float*)alloc((size_t)G_ * chx * M_ * 4);
  ushortt* Khi   = (ushortt*)alloc((size_t)G_ * chx * M_ * 2);
  ushortt* Klo   = (ushortt*)alloc((size_t)G_ * chx * M_ * 2);

  int chx64 = chx / 64;
  int T = 12 * chx64;      // kufg tiles in chunk 0 (both g)
  int Th = T / 2;          // half fused with each inversion; Th/4 blocks

  // ---- merged prep: patchnorm + Zt/znorm/out-init + Kuu tiles ----
  k_prep<<<PNB_ + P1B_ + 288, 512, 0, stream>>>(
      xin, Z, vptr, lptr, Zt, znorm, outp, pat, pnorm, Kuu64, Kuu32);

  // ---- fp32 seed: Kinv32 via 2x2 block Schur (192+192); inversions fused
  //      with chunk-0 Kuf tiles (independent work on otherwise-idle CUs) ----
  k_invkufg<<<G_ + Th / 4, 1024, 0, stream>>>(
      Kuu32, Kinv32, pat, Zt, znorm, pnorm, vptr, lptr,
      Kx, Khi, Klo, 0, chx, 0);
  k_sgemm<<<dim3(6, 6, G_), 512, 0, stream>>>(
      Kinv32, M_, 0, MM_, Kuu32 + 192, M_, 0, 0, MM_,
      nullptr, 0, 0.0f, 1.0f, 0,
      Ebuf, 192, 192 * 192, nullptr, 0, 0, nullptr, nullptr, 192, 192, 192);
  k_sgemm<<<dim3(6, 6, G_), 512, 0, stream>>>(
      Kuu32 + 192, M_, 1, MM_, Ebuf, 192, 0, 0, 192 * 192,
      Kuu32 + 192 * M_ + 192, MM_, 1.0f, -1.0f, 0,
      Kuu32 + 192 * M_ + 192, M_, MM_, nullptr, 0, 0, nullptr, nullptr, 192, 192, 192);
  k_invkufg<<<G_ + Th / 4, 1024, 0, stream>>>(
      Kuu32 + 192 * M_ + 192, Kinv32 + 192 * M_ + 192, pat, Zt, znorm, pnorm,
      vptr, lptr, Kx, Khi, Klo, 0, chx, Th);
  k_sgemm<<<dim3(6, 6, G_), 512, 0, stream>>>(
      Ebuf, 192, 0, 192 * 192, Kinv32 + 192 * M_ + 192, M_, 0, 0, MM_,
      nullptr, 0, 0.0f, -1.0f, 0,
      Kinv32 + 192, M_, MM_, Kinv32 + 192 * M_, M_, MM_, nullptr, nullptr, 192, 192, 192);
  k_sgemm<<<dim3(6, 6, G_), 512, 0, stream>>>(
      Kinv32 + 192, M_, 0, MM_, Ebuf, 192, 1, 0, 192 * 192,
      Kinv32, MM_, 1.0f, -1.0f, 0,
      Kinv32, M_, MM_, nullptr, 0, 0, nullptr, nullptr, 192, 192, 192);

  // ---- Newton residual in fp64 (the only cancellation-critical GEMM):
  //      R = I - Kuu64*X0, output fp32 ----
  k_dgemmx<<<dim3(12, 12, G_), 512, 0, stream>>>(
      Kuu64, 1, M_, 0, (size_t)MM_,
      Kinv32, 0, M_, 0, 0, (size_t)MM_,
      nullptr, 0, 0, 0.0,
      -1.0, 1, nullptr, M_, (size_t)MM_, Rf, nullptr, nullptr, M_, M_, M_);
  // ---- X2 = X0 + X0*R : fp32 ----
  k_sgemm<<<dim3(12, 12, G_), 512, 0, stream>>>(
      Kinv32, M_, 0, MM_, Rf, M_, 0, 0, MM_,
      Kinv32, MM_, 1.0f, 1.0f, 0,
      Xf, M_, MM_, nullptr, 0, 0, nullptr, nullptr, M_, M_, M_);

  // ---- V = X2 * tril(Lq) : fp32 with exact-zero k-tile skip ----
  k_sgemm<<<dim3(12, 12, G_), 512, 0, stream>>>(
      Xf, M_, 0, MM_, qsqrt, M_, 0, 1, MM_,
      nullptr, 0, 0.0f, 1.0f, 0,
      Rf, M_, MM_, nullptr, 0, 0, nullptr, nullptr, M_, M_, M_);       // Rf = V
  // ---- S = V*V^T - X2 -> bf16 hi/lo; symmetric: lower tiles + mirror ----
  k_sgemm<<<dim3(12, 12, G_), 512, 0, stream>>>(
      Rf, M_, 0, MM_, Rf, M_, 1, 0, MM_,
      Xf, MM_, -1.0f, 1.0f, 0,
      nullptr, M_, MM_, nullptr, 0, 0, Shi, Slo, M_, M_, M_);
  k_cvec32<<<(G_ * M_ + 255) / 256, 256, 0, stream>>>(Xf, qmu, cvec);

  // ---- per-chunk: chunk 0's K already built by the fused kernels ----
  for (int ch = 0; ch < nc; ++ch) {
    int x0 = ch * chx;
    if (ch > 0)
      k_kufg<<<dim3(M_ / 64, chx / 64, G_), 256, 0, stream>>>(
          pat, Zt, znorm, pnorm, vptr, lptr, Kx, Khi, Klo, x0, chx);
    k_ufoldm<<<dim3(1, chx / 64, G_), 256, 0, stream>>>(
        Khi, Klo, Kx, Shi, Slo, cvec, vptr, outp, x0, chx);
  }
}

// Round 13
// 879.207 us; speedup vs baseline: 1.0049x; 1.0049x over previous
//
#include <hip/hip_runtime.h>
#include <hip/hip_bf16.h>

typedef unsigned short ushortt;
typedef __attribute__((ext_vector_type(8))) short short8v;
typedef __attribute__((ext_vector_type(4))) float f32x4;

#define H_ 32
#define W_ 32
#define C_ 3
#define PH_ 5
#define PW_ 5
#define HP_ 28
#define WP_ 28
#define P_ 784
#define N_ 32
#define L_ 75
#define LP_ 80            /* padded L for float4 staging */
#define G_ 2
#define M_ 384
#define MM_ (M_*M_)       /* 147456 */
#define PN_ (P_*N_)       /* 25088 */
#define JITTER_ 1e-6
#define PNB_ 3136         /* patchnorm blocks: PN_/8 */
#define P1B_ 113          /* prep1 blocks: ceil(G_*L_*M_/512) */

__device__ __forceinline__ float bf2f(ushortt u) {
  return __uint_as_float(((unsigned int)u) << 16);
}
__device__ __forceinline__ ushortt f2bf(float f) {
  __hip_bfloat16 h = __float2bfloat16(f);
  ushortt u;
  __builtin_memcpy(&u, &h, sizeof(u));
  return u;
}

// accurate exp(t) for t <= 0, fp64
__device__ __forceinline__ double exp64(double t) {
  double y = t * 1.4426950408889634;
  double nn = rint(y);
  double z = (y - nn) * 0.6931471805599453;
  double e = 1.6059043836821613e-10;
  e = fma(e, z, 2.08767569878681e-9);
  e = fma(e, z, 2.505210838544172e-8);
  e = fma(e, z, 2.755731922398589e-7);
  e = fma(e, z, 2.7557319223985893e-6);
  e = fma(e, z, 2.48015873015873e-5);
  e = fma(e, z, 1.984126984126984e-4);
  e = fma(e, z, 1.3888888888888889e-3);
  e = fma(e, z, 8.333333333333333e-3);
  e = fma(e, z, 4.1666666666666664e-2);
  e = fma(e, z, 1.6666666666666666e-1);
  e = fma(e, z, 0.5);
  e = fma(e, z, 1.0);
  e = fma(e, z, 1.0);
  return ldexp(e, (int)nn);
}

// ================= merged prep: patchnorm (blocks 0..PNB_-1),
//                   Zt/znorm/out-init (next P1B_), Kuu tiles (last 288) ======
__global__ __launch_bounds__(512) void k_prep(
    const float* __restrict__ xin, const float* __restrict__ Z,
    const float* vptr, const float* lptr,
    float* __restrict__ Zt, float* __restrict__ znorm,
    float* __restrict__ outp, float* __restrict__ pat,
    float* __restrict__ pnorm,
    double* __restrict__ Kuu64, float* __restrict__ Kuu32) {
  int b = blockIdx.x;
  if (b < PNB_) {
    // ---- patchnorm: 8 waves/block, one wave per x ----
    int wv = threadIdx.x >> 6;
    int t = threadIdx.x & 63;
    int x = b * 8 + wv;
    int n = x & 31, p = x >> 5;
    int hp = p / WP_, wp = p % WP_;
    const float* xb = xin + n * (H_ * W_ * C_);
    auto pval = [&](int l) -> float {
      if (l >= L_) return 0.f;
      int q = l / C_, c = l % C_;
      int i = q / PW_, j = q % PW_;
      return xb[((hp + i) * W_ + (wp + j)) * C_ + c];
    };
    float v1 = pval(t);
    float v2 = (t < 16) ? pval(t + 64) : 0.f;
    pat[(size_t)x * LP_ + t] = v1;
    if (t < 16) pat[(size_t)x * LP_ + 64 + t] = v2;
    float s = v1 * v1 + v2 * v2;
#pragma unroll
    for (int off = 32; off; off >>= 1) s += __shfl_down(s, off);
    if (t == 0) pnorm[x] = s;
    return;
  }
  if (b < PNB_ + P1B_) {
    // ---- Zt transpose + znorm + output init ----
    int idx = (b - PNB_) * 512 + threadIdx.x;
    if (idx < G_ * L_ * M_) {
      int m = idx % M_;
      int l = (idx / M_) % L_;
      int g = idx / (M_ * L_);
      Zt[idx] = Z[(g * M_ + m) * L_ + l];
    }
    if (idx < G_ * M_) {
      const float* zr = Z + (size_t)idx * L_;
      float s = 0.f;
      for (int l = 0; l < L_; ++l) s = fmaf(zr[l], zr[l], s);
      znorm[idx] = s;
    }
    if (idx < PN_ * G_) {
      outp[idx] = 0.f;
      outp[PN_ * G_ + idx] = vptr[0];
    }
    return;
  }
  // ---- Kuu fp64 + fp32 copy: tiled, 32x32 per block ----
  int q = b - PNB_ - P1B_;
  int bx = q % 12, by = (q / 12) % 12, g = q / 144;
  int row0 = by * 32, col0 = bx * 32;
  __shared__ float Zr[32][76], Zc[32][76];
  int t = threadIdx.x;
  for (int idx = t; idx < 2400; idx += 512) {
    int r = idx / 75, l = idx % 75;
    Zr[r][l] = Z[((size_t)(g * M_ + row0 + r)) * L_ + l];
    Zc[r][l] = Z[((size_t)(g * M_ + col0 + r)) * L_ + l];
  }
  __syncthreads();

  int ty = t >> 4, tx = t & 15;
  double s0 = 0.0, s1 = 0.0;
#pragma unroll 5
  for (int l = 0; l < 75; ++l) {
    double zi = (double)Zr[ty][l];
    double d0 = zi - (double)Zc[tx][l];
    double d1 = zi - (double)Zc[tx + 16][l];
    s0 = fma(d0, d0, s0);
    s1 = fma(d1, d1, s1);
  }
  double v = (double)vptr[0], ls = (double)lptr[0];
  double inv2 = -0.5 / (ls * ls);
  int r = row0 + ty;
  double ss[2] = {s0, s1};
#pragma unroll
  for (int cc = 0; cc < 2; ++cc) {
    int j = col0 + tx + cc * 16;
    double val = v * exp64(ss[cc] * inv2);
    if (r == j) val += JITTER_;
    size_t o = (size_t)g * MM_ + (size_t)r * M_ + j;
    Kuu64[o] = val;
    Kuu32[o] = (float)val;
  }
}

// ================= fused: 192x192 blocked GJ inverse (blocks 0..1) =================
// ================= + Kuf-build tiles (blocks 2..)                  =================
// r8-verified structure (measured 104-105us/dispatch): Pinv via LDS,
// single-wave phase 2. (r9's all-wave redundant shuffle inversion regressed
// to 145us: __shfl = ds_bpermute = LDS pipe; 16x traffic.)
__global__ __launch_bounds__(1024, 1) void k_invkufg(
    const float* __restrict__ Ain, float* __restrict__ Aout,
    const float* __restrict__ pat, const float* __restrict__ Zt,
    const float* __restrict__ znorm, const float* __restrict__ pnorm,
    const float* vptr, const float* lptr,
    float* __restrict__ Kx, ushortt* __restrict__ Khi, ushortt* __restrict__ Klo,
    int x0, int chx, int tile0) {
  __shared__ __align__(16) char smem[37888];

  if (blockIdx.x < G_) {
    // ---------------- inversion path ----------------
    __builtin_amdgcn_s_setprio(1);
    float (*rowb)[192]  = (float(*)[192])(smem);           // pivot-row panel R
    float (*rowb2)[192] = (float(*)[192])(smem + 12288);   // R' = Pinv * R
    float (*colbT)[192] = (float(*)[192])(smem + 24576);   // colbT[k][i]
    float (*Pinv)[16]   = (float(*)[16])(smem + 36864);

    int g = blockIdx.x;
    const float* A = Ain + (size_t)g * MM_;
    float* O = Aout + (size_t)g * MM_;
    int t = threadIdx.x;
    int rid = t >> 5, cid = t & 31;
    int r0 = rid * 6, c0 = cid * 6;

    float a[6][6];
#pragma unroll
    for (int ii = 0; ii < 6; ++ii) {
#pragma unroll
      for (int j2 = 0; j2 < 3; ++j2) {
        float2 v = *(const float2*)&A[(size_t)(r0 + ii) * M_ + c0 + j2 * 2];
        a[ii][j2 * 2 + 0] = v.x; a[ii][j2 * 2 + 1] = v.y;
      }
    }

    for (int bs = 0; bs < 12; ++bs) {
      int kp = bs * 16;
      // ---- phase 1: publish panels from registers ----
#pragma unroll
      for (int ii = 0; ii < 6; ++ii) {
        int k = r0 + ii - kp;
        if ((unsigned)k < 16u) {
#pragma unroll
          for (int jj = 0; jj < 6; ++jj) rowb[k][c0 + jj] = a[ii][jj];
        }
      }
#pragma unroll
      for (int jj = 0; jj < 6; ++jj) {
        int c = c0 + jj - kp;
        if ((unsigned)c < 16u) {
#pragma unroll
          for (int ii = 0; ii < 6; ++ii) colbT[c][r0 + ii] = a[ii][jj];
        }
      }
      __syncthreads();

      // ---- phase 2: wave 0 inverts 16x16 pivot block in registers ----
      if (t < 64) {
        int r = t >> 2, cg = t & 3;
        float vals[4];
#pragma unroll
        for (int j = 0; j < 4; ++j) vals[j] = rowb[r][kp + cg * 4 + j];
#pragma unroll
        for (int k = 0; k < 16; ++k) {
          const int cgk = k >> 2, jk = k & 3;
          float pkk = __shfl(vals[jk], k * 4 + cgk);
          float c_ = __shfl(vals[jk], (t & 0x3c) | cgk);
          float p = 1.0f / pkk;
          float cp = c_ * p;
          bool pivRow = (r == k);
#pragma unroll
          for (int j = 0; j < 4; ++j) {
            float prj = __shfl(vals[j], k * 4 + cg);
            bool pivCol = (cg == cgk) && (j == jk);
            float gen = fmaf(-cp, prj, vals[j]);
            float nv = pivRow ? (pivCol ? p : p * prj)
                              : (pivCol ? -cp : gen);
            vals[j] = nv;
          }
        }
#pragma unroll
        for (int j = 0; j < 4; ++j) Pinv[r][cg * 4 + j] = vals[j];
      }
      __syncthreads();

      // ---- phase 3: rowb2 <- Pinv * rowb, all 1024 threads ----
      {
        int r = t >> 6;
        float pv[16];
#pragma unroll
        for (int m = 0; m < 16; ++m) pv[m] = Pinv[r][m];
#pragma unroll
        for (int rep = 0; rep < 3; ++rep) {
          int c = (t & 63) + 64 * rep;
          int cc = c - kp;
          float s;
          if ((unsigned)cc < 16u) {
            s = pv[cc];
          } else {
            s = 0.f;
#pragma unroll
            for (int m = 0; m < 16; ++m) s = fmaf(pv[m], rowb[m][c], s);
          }
          rowb2[r][c] = s;
        }
      }
      __syncthreads();

      // ---- phase 4: rank-16 update (bounded unroll: no spill) ----
#pragma unroll
      for (int jj = 0; jj < 6; ++jj) {
        int c = c0 + jj - kp;
        if ((unsigned)c < 16u) {
#pragma unroll
          for (int ii = 0; ii < 6; ++ii) a[ii][jj] = 0.f;
        }
      }
#pragma unroll 2
      for (int k = 0; k < 16; ++k) {
        float rk[6], ck[6];
#pragma unroll
        for (int j2 = 0; j2 < 3; ++j2) {
          float2 v = *(const float2*)&rowb2[k][c0 + j2 * 2];
          rk[j2 * 2 + 0] = v.x; rk[j2 * 2 + 1] = v.y;
        }
#pragma unroll
        for (int i2 = 0; i2 < 3; ++i2) {
          float2 v = *(const float2*)&colbT[k][r0 + i2 * 2];
          ck[i2 * 2 + 0] = v.x; ck[i2 * 2 + 1] = v.y;
        }
#pragma unroll
        for (int ii = 0; ii < 6; ++ii)
#pragma unroll
          for (int jj = 0; jj < 6; ++jj)
            a[ii][jj] = fmaf(-ck[ii], rk[jj], a[ii][jj]);
      }
      // pivot rows: overwrite with R'
#pragma unroll
      for (int ii = 0; ii < 6; ++ii) {
        int k = r0 + ii - kp;
        if ((unsigned)k < 16u) {
#pragma unroll
          for (int jj = 0; jj < 6; ++jj) a[ii][jj] = rowb2[k][c0 + jj];
        }
      }
      __syncthreads();
    }

#pragma unroll
    for (int ii = 0; ii < 6; ++ii) {
#pragma unroll
      for (int j2 = 0; j2 < 3; ++j2) {
        float2 v = {a[ii][j2 * 2 + 0], a[ii][j2 * 2 + 1]};
        *(float2*)&O[(size_t)(r0 + ii) * M_ + c0 + j2 * 2] = v;
      }
    }
    return;
  }

  // ---------------- kufg path: 4 groups x one 64x64 tile ----------------
  typedef float lds68[16][68];
  lds68* As = (lds68*)(smem);            // As[grp][k][r]
  lds68* Bs = (lds68*)(smem + 17408);    // Bs[grp][k][c]

  int bid = (int)blockIdx.x - G_;
  int grp = threadIdx.x >> 8;
  int t = threadIdx.x & 255;
  int tile = tile0 + bid * 4 + grp;
  int chx64 = chx >> 6;
  int col = tile % 6;
  int rg = tile / 6;
  int g = rg / chx64;
  int row = rg % chx64;
  int col0 = col * 64;
  int row0 = row * 64;
  int tr = t >> 4, tc = t & 15;
  float acc[4][4] = {};

  for (int kt = 0; kt < LP_; kt += 16) {
    {
      int r = t >> 2, k4 = (t & 3) * 4;
      float4 av = *(const float4*)&pat[(size_t)(x0 + row0 + r) * LP_ + kt + k4];
      As[grp][k4 + 0][r] = av.x;
      As[grp][k4 + 1][r] = av.y;
      As[grp][k4 + 2][r] = av.z;
      As[grp][k4 + 3][r] = av.w;
    }
    {
      int k = t >> 4, c4 = (t & 15) * 4;
      float4 bv = {0.f, 0.f, 0.f, 0.f};
      if (kt + k < L_)
        bv = *(const float4*)&Zt[((size_t)(g * L_ + kt + k)) * M_ + col0 + c4];
      *(float4*)&Bs[grp][k][c4] = bv;
    }
    __syncthreads();
#pragma unroll 4
    for (int k = 0; k < 16; ++k) {
      float4 av = *(const float4*)&As[grp][k][tr * 4];
      float4 bv = *(const float4*)&Bs[grp][k][tc * 4];
      float a4[4] = {av.x, av.y, av.z, av.w};
      float b4[4] = {bv.x, bv.y, bv.z, bv.w};
#pragma unroll
      for (int i = 0; i < 4; ++i)
#pragma unroll
        for (int j = 0; j < 4; ++j) acc[i][j] = fmaf(a4[i], b4[j], acc[i][j]);
    }
    __syncthreads();
  }
  float v = vptr[0], ls = lptr[0];
  float c2 = -0.72134752044f / (ls * ls);
#pragma unroll
  for (int i = 0; i < 4; ++i) {
    int xl = row0 + tr * 4 + i;
    float pn = pnorm[x0 + xl];
    float tmp[4];
    ushortt hi[4], lo[4];
#pragma unroll
    for (int j = 0; j < 4; ++j) {
      int m = col0 + tc * 4 + j;
      float sq = znorm[g * M_ + m] + pn - 2.0f * acc[i][j];
      tmp[j] = v * exp2f(sq * c2);
      hi[j] = f2bf(tmp[j]);
      lo[j] = f2bf(tmp[j] - bf2f(hi[j]));
    }
    size_t base = ((size_t)g * chx + xl) * M_ + col0 + tc * 4;
    float4 ov = {tmp[0], tmp[1], tmp[2], tmp[3]};
    *(float4*)&Kx[base] = ov;
    *(ushort4*)&Khi[base] = make_ushort4(hi[0], hi[1], hi[2], hi[3]);
    *(ushort4*)&Klo[base] = make_ushort4(lo[0], lo[1], lo[2], lo[3]);
  }
}

// ---------------- fp32 tiled GEMM ----------------
__global__ __launch_bounds__(512) void k_sgemm(
    const float* __restrict__ A, int lda, int tA, int sAg,
    const float* __restrict__ B, int ldb, int tB, int btril, int sBg,
    const float* __restrict__ Cin, int sCing, float beta,
    float alpha, int addI,
    float* __restrict__ Cout, int ldc, int sCg,
    float* __restrict__ CoutT, int ldt, int sTg,
    ushortt* __restrict__ shiOut, ushortt* __restrict__ sloOut,
    int M, int N, int K) {
  int g = blockIdx.z;
  int row0 = blockIdx.y * 32, col0 = blockIdx.x * 32;
  if (shiOut && col0 > row0) return;   // symmetric output: lower tiles only
  A += (size_t)g * sAg;
  B += (size_t)g * sBg;
  if (Cin) Cin += (size_t)g * sCing;
  if (Cout) Cout += (size_t)g * sCg;
  if (CoutT) CoutT += (size_t)g * sTg;
  if (shiOut) { shiOut += (size_t)g * sCg; sloOut += (size_t)g * sCg; }

  __shared__ __align__(16) float As[32][34], Bs[32][34];
  int t = threadIdx.x;
  int tx = t & 15, ty = t >> 4;
  float acc0 = 0.f, acc1 = 0.f;

  int kt0 = btril ? (col0 & ~31) : 0;  // tiles fully above tril are exact zeros
  for (int kt = kt0; kt < K; kt += 32) {
    for (int idx = t; idx < 1024; idx += 512) {
      int rr = idx >> 5, cc = idx & 31;
      {
        int gr = row0 + rr, gk = kt + cc;
        As[rr][cc] = tA ? A[(size_t)gk * lda + gr] : A[(size_t)gr * lda + gk];
      }
      {
        int gk = kt + rr, gc = col0 + cc;
        float bv = tB ? B[(size_t)gc * ldb + gk] : B[(size_t)gk * ldb + gc];
        if (btril && gc > gk) bv = 0.f;
        Bs[rr][cc] = bv;
      }
    }
    __syncthreads();
#pragma unroll 8
    for (int kk = 0; kk < 32; ++kk) {
      float a0 = As[ty][kk];
      float2 b = *(const float2*)&Bs[kk][tx * 2];
      acc0 = fmaf(a0, b.x, acc0);
      acc1 = fmaf(a0, b.y, acc1);
    }
    __syncthreads();
  }
  float accs[2] = {acc0, acc1};
#pragma unroll
  for (int b2 = 0; b2 < 2; ++b2) {
    int gr = row0 + ty, gc = col0 + tx * 2 + b2;
    float val = alpha * accs[b2];
    if (addI && gr == gc) val += 1.0f;
    if (Cin) val += beta * Cin[(size_t)gr * ldc + gc];
    if (Cout) Cout[(size_t)gr * ldc + gc] = val;
    if (CoutT) CoutT[(size_t)gc * ldt + gr] = val;
    if (shiOut) {
      ushortt h = f2bf(val);
      shiOut[(size_t)gr * ldc + gc] = h;
      sloOut[(size_t)gr * ldc + gc] = f2bf(val - bf2f(h));
      // mirror: acc symmetric; use transposed Cin element for exactness
      float vm = alpha * accs[b2];
      if (Cin) vm += beta * Cin[(size_t)gc * ldc + gr];
      ushortt hm = f2bf(vm);
      shiOut[(size_t)gc * ldc + gr] = hm;
      sloOut[(size_t)gc * ldc + gr] = f2bf(vm - bf2f(hm));
    }
  }
}

// ---------------- mixed-precision fp64-accum GEMM (Newton residual only) ----------------
__global__ __launch_bounds__(512) void k_dgemmx(
    const void* __restrict__ Ap, int aF64, int lda, int tA, size_t sAg,
    const void* __restrict__ Bp, int bF64, int ldb, int tB, int btril, size_t sBg,
    const void* __restrict__ Cp, int cF64, size_t sCing, double beta,
    double alpha, int addI,
    double* __restrict__ Cout, int ldc, size_t sCg,
    float* __restrict__ f32out,
    ushortt* __restrict__ shiOut, ushortt* __restrict__ sloOut,
    int M, int N, int K) {
  int g = blockIdx.z;
  const double* A64 = (const double*)Ap + (size_t)g * sAg;
  const float* A32 = (const float*)Ap + (size_t)g * sAg;
  const double* B64 = (const double*)Bp + (size_t)g * sBg;
  const float* B32 = (const float*)Bp + (size_t)g * sBg;
  const double* C64 = Cp ? (const double*)Cp + (size_t)g * sCing : nullptr;
  const float* C32 = Cp ? (const float*)Cp + (size_t)g * sCing : nullptr;
  if (Cout) Cout += (size_t)g * sCg;
  if (f32out) f32out += (size_t)g * sCg;
  if (shiOut) shiOut += (size_t)g * sCg;
  if (sloOut) sloOut += (size_t)g * sCg;

  __shared__ __align__(16) double As[32][34], Bs[32][34];
  int t = threadIdx.x;
  int tx = t & 15, ty = t >> 4;
  int row0 = blockIdx.y * 32, col0 = blockIdx.x * 32;
  double acc0 = 0., acc1 = 0.;

  for (int kt = 0; kt < K; kt += 32) {
    for (int idx = t; idx < 1024; idx += 512) {
      int rr = idx >> 5, cc = idx & 31;
      {
        int gr = row0 + rr, gk = kt + cc;
        size_t ai = tA ? ((size_t)gk * lda + gr) : ((size_t)gr * lda + gk);
        As[rr][cc] = aF64 ? A64[ai] : (double)A32[ai];
      }
      {
        int gk = kt + rr, gc = col0 + cc;
        size_t bi = tB ? ((size_t)gc * ldb + gk) : ((size_t)gk * ldb + gc);
        double bv = bF64 ? B64[bi] : (double)B32[bi];
        if (btril && gc > gk) bv = 0.0;
        Bs[rr][cc] = bv;
      }
    }
    __syncthreads();
#pragma unroll 8
    for (int kk = 0; kk < 32; ++kk) {
      double a0 = As[ty][kk];
      double2 b = *(const double2*)&Bs[kk][tx * 2];
      acc0 = fma(a0, b.x, acc0);
      acc1 = fma(a0, b.y, acc1);
    }
    __syncthreads();
  }
  double accs[2] = {acc0, acc1};
#pragma unroll
  for (int b2 = 0; b2 < 2; ++b2) {
    int gr = row0 + ty, gc = col0 + tx * 2 + b2;
    double val = alpha * accs[b2];
    if (addI && gr == gc) val += 1.0;
    if (C64) {
      double cv = cF64 ? C64[(size_t)gr * ldc + gc] : (double)C32[(size_t)gr * ldc + gc];
      val += beta * cv;
    }
    if (Cout) Cout[(size_t)gr * ldc + gc] = val;
    if (f32out) f32out[(size_t)gr * ldc + gc] = (float)val;
    if (shiOut) {
      float sv = (float)val;
      ushortt h = f2bf(sv);
      shiOut[(size_t)gr * ldc + gc] = h;
      sloOut[(size_t)gr * ldc + gc] = f2bf(sv - bf2f(h));
    }
  }
}

// ---------------- c_g = X * q_mu[:,g]  (fp32 X, fp64 accum) ----------------
__global__ void k_cvec32(const float* __restrict__ X, const float* __restrict__ qmu,
                         float* __restrict__ cvec) {
  int idx = blockIdx.x * 256 + threadIdx.x;
  if (idx >= G_ * M_) return;
  int m = idx % M_, g = idx / M_;
  const float* row = X + (size_t)g * MM_ + (size_t)m * M_;
  double s = 0.0;
  for (int k = 0; k < M_; ++k) s = fma((double)row[k], (double)qmu[k * G_ + g], s);
  cvec[idx] = (float)s;
}

// ---------------- Kuf as GEMM (64x64 tile) -> Kx fp32 + Khi/Klo bf16 ----------------
// (standalone version, used for chunks >= 1 when nc > 1)
__global__ __launch_bounds__(256) void k_kufg(const float* __restrict__ pat,
                                              const float* __restrict__ Zt,
                                              const float* __restrict__ znorm,
                                              const float* __restrict__ pnorm,
                                              const float* vptr, const float* lptr,
                                              float* __restrict__ Kx,
                                              ushortt* __restrict__ Khi,
                                              ushortt* __restrict__ Klo,
                                              int x0, int chx) {
  int g = blockIdx.z;
  int col0 = blockIdx.x * 64;
  int row0 = blockIdx.y * 64;
  __shared__ __align__(16) float As[16][68];
  __shared__ __align__(16) float Bs[16][68];
  int t = threadIdx.x;
  int tr = t >> 4, tc = t & 15;
  float acc[4][4] = {};

  for (int kt = 0; kt < LP_; kt += 16) {
    {
      int r = t >> 2, k4 = (t & 3) * 4;
      float4 av = *(const float4*)&pat[(size_t)(x0 + row0 + r) * LP_ + kt + k4];
      As[k4 + 0][r] = av.x;
      As[k4 + 1][r] = av.y;
      As[k4 + 2][r] = av.z;
      As[k4 + 3][r] = av.w;
    }
    {
      int k = t >> 4, c4 = (t & 15) * 4;
      float4 bv = {0.f, 0.f, 0.f, 0.f};
      if (kt + k < L_)
        bv = *(const float4*)&Zt[((size_t)(g * L_ + kt + k)) * M_ + col0 + c4];
      *(float4*)&Bs[k][c4] = bv;
    }
    __syncthreads();
#pragma unroll
    for (int k = 0; k < 16; ++k) {
      float4 av = *(const float4*)&As[k][tr * 4];
      float4 bv = *(const float4*)&Bs[k][tc * 4];
      float a4[4] = {av.x, av.y, av.z, av.w};
      float b4[4] = {bv.x, bv.y, bv.z, bv.w};
#pragma unroll
      for (int i = 0; i < 4; ++i)
#pragma unroll
        for (int j = 0; j < 4; ++j) acc[i][j] = fmaf(a4[i], b4[j], acc[i][j]);
    }
    __syncthreads();
  }
  float v = vptr[0], ls = lptr[0];
  float c2 = -0.72134752044f / (ls * ls);
#pragma unroll
  for (int i = 0; i < 4; ++i) {
    int xl = row0 + tr * 4 + i;
    float pn = pnorm[x0 + xl];
    float tmp[4];
    ushortt hi[4], lo[4];
#pragma unroll
    for (int j = 0; j < 4; ++j) {
      int m = col0 + tc * 4 + j;
      float sq = znorm[g * M_ + m] + pn - 2.0f * acc[i][j];
      tmp[j] = v * exp2f(sq * c2);
      hi[j] = f2bf(tmp[j]);
      lo[j] = f2bf(tmp[j] - bf2f(hi[j]));
    }
    size_t base = ((size_t)g * chx + xl) * M_ + col0 + tc * 4;
    float4 ov = {tmp[0], tmp[1], tmp[2], tmp[3]};
    *(float4*)&Kx[base] = ov;
    *(ushort4*)&Khi[base] = make_ushort4(hi[0], hi[1], hi[2], hi[3]);
    *(ushort4*)&Klo[base] = make_ushort4(lo[0], lo[1], lo[2], lo[3]);
  }
}

// ---------------- LDS frag helper: 16B-aligned read -> short8v ----------------
__device__ __forceinline__ short8v lds_frag(const ushortt* p) {
  int4 v = *(const int4*)p;
  short8v r;
  __builtin_memcpy(&r, &v, 16);
  return r;
}

// ---------------- MFMA U-GEMM + fold, LDS-staged ----------------
// r13: 64-row x 384-col block, processed as TWO passes of 192 cols.
// r12 post-mortem: single-pass acc[24] (96 VGPR) spilled at the compiler's
// 88-VGPR choice -> 966MB scratch writes, 410us. Two passes keep acc[12]
// (48 VGPR) + persistent fp64 partials pv/pm (16 VGPR) -> demand ~100, no
// spill. Retains r11's traffic goals: K-panels ~1x HBM (pass-2 A re-read is
// L2-hit: 98KB/block), direct stores (each output owned by one block).
// LDS: A 2x5KB + B 2x15KB + cs = ~42KB -> 3 blocks/CU.
#define STR_ 40
__global__ __launch_bounds__(256) void k_ufoldm(
    const ushortt* __restrict__ Khi, const ushortt* __restrict__ Klo,
    const float* __restrict__ Kx32,
    const ushortt* __restrict__ Shi, const ushortt* __restrict__ Slo,
    const float* __restrict__ cvec, const float* vptr,
    float* __restrict__ outp, int x0, int chx) {
  int g = blockIdx.z;
  int row0 = blockIdx.y * 64;
  const ushortt* Ahg = Khi + (size_t)g * chx * M_;
  const ushortt* Alg = Klo + (size_t)g * chx * M_;
  const float* A32 = Kx32 + (size_t)g * chx * M_;
  const ushortt* Bhg = Shi + (size_t)g * MM_;
  const ushortt* Blg = Slo + (size_t)g * MM_;

  __shared__ __align__(16) ushortt Ahs[64][STR_], Als[64][STR_];
  __shared__ __align__(16) ushortt Bhs[192][STR_], Bls[192][STR_];
  __shared__ float cs[384];

  int t = threadIdx.x;
  cs[t] = cvec[g * M_ + t];
  if (t < 128) cs[256 + t] = cvec[g * M_ + 256 + t];

  int w = t >> 6, lane = t & 63, n15 = lane & 15, q = lane >> 4;
  int q8 = q * 8;

  double pv[4] = {0.0, 0.0, 0.0, 0.0};
  double pm[4] = {0.0, 0.0, 0.0, 0.0};

  for (int half = 0; half < 2; ++half) {
    f32x4 acc[12];
#pragma unroll
    for (int ct = 0; ct < 12; ++ct) acc[ct] = (f32x4){0.f, 0.f, 0.f, 0.f};

    for (int kt = 0; kt < M_; kt += 32) {
      __syncthreads();   // prior iteration / prior half readers done
      // stage A (64 rows x 32k, hi+lo): threads 0..127
      if (t < 128) {
        int sr = t >> 1, sk = (t & 1) * 16;
        size_t abase = (size_t)(row0 + sr) * M_ + kt + sk;
        uint4 a0 = *(const uint4*)&Ahg[abase];
        uint4 a1 = *(const uint4*)&Ahg[abase + 8];
        *(uint4*)&Ahs[sr][sk] = a0;
        *(uint4*)&Ahs[sr][sk + 8] = a1;
        uint4 b0 = *(const uint4*)&Alg[abase];
        uint4 b1 = *(const uint4*)&Alg[abase + 8];
        *(uint4*)&Als[sr][sk] = b0;
        *(uint4*)&Als[sr][sk + 8] = b1;
      }
      // stage B (rows half*192 .. half*192+191, hi+lo): 384 slots
#pragma unroll
      for (int rep = 0; rep < 2; ++rep) {
        int s = t + 256 * rep;
        if (s < 384) {
          int sr = s >> 1, sk = (s & 1) * 16;
          size_t bbase = (size_t)(half * 192 + sr) * M_ + kt + sk;
          uint4 c0 = *(const uint4*)&Bhg[bbase];
          uint4 c1 = *(const uint4*)&Bhg[bbase + 8];
          *(uint4*)&Bhs[sr][sk] = c0;
          *(uint4*)&Bhs[sr][sk + 8] = c1;
          uint4 d0 = *(const uint4*)&Blg[bbase];
          uint4 d1 = *(const uint4*)&Blg[bbase + 8];
          *(uint4*)&Bls[sr][sk] = d0;
          *(uint4*)&Bls[sr][sk + 8] = d1;
        }
      }
      __syncthreads();

      short8v ahi = lds_frag(&Ahs[w * 16 + n15][q8]);
      short8v alo = lds_frag(&Als[w * 16 + n15][q8]);
#pragma unroll 4
      for (int ct = 0; ct < 12; ++ct) {
        short8v bhi = lds_frag(&Bhs[ct * 16 + n15][q8]);
        short8v blo = lds_frag(&Bls[ct * 16 + n15][q8]);
        acc[ct] = __builtin_amdgcn_mfma_f32_16x16x32_bf16(ahi, bhi, acc[ct], 0, 0, 0);
        acc[ct] = __builtin_amdgcn_mfma_f32_16x16x32_bf16(ahi, blo, acc[ct], 0, 0, 0);
        acc[ct] = __builtin_amdgcn_mfma_f32_16x16x32_bf16(alo, bhi, acc[ct], 0, 0, 0);
      }
    }

    // fold this half's 192 cols into persistent fp64 partials
#pragma unroll
    for (int reg = 0; reg < 4; ++reg) {
      int xr2 = row0 + w * 16 + q * 4 + reg;
      const float* arow = &A32[(size_t)xr2 * M_ + half * 192];
#pragma unroll 4
      for (int ct = 0; ct < 12; ++ct) {
        int col = ct * 16 + n15;
        float kval = arow[col];
        pv[reg] += (double)kval * acc[ct][reg];
        pm[reg] += (double)kval * cs[half * 192 + col];
      }
    }
  }

  // reduce across the 16 lanes of each quarter-wave row group; direct store
  float var0 = vptr[0];
#pragma unroll
  for (int reg = 0; reg < 4; ++reg) {
    double v2 = pv[reg], m2 = pm[reg];
#pragma unroll
    for (int mk = 1; mk < 16; mk <<= 1) {
      v2 += __shfl_xor(v2, mk, 16);
      m2 += __shfl_xor(m2, mk, 16);
    }
    if (n15 == 0) {
      int xr2 = row0 + w * 16 + q * 4 + reg;
      int x = x0 + xr2;
      int p = x >> 5, n = x & 31;
      int oidx = n * (P_ * G_) + p * G_ + g;
      outp[oidx] = (float)m2;
      outp[PN_ * G_ + oidx] = var0 + (float)v2;
    }
  }
}

extern "C" void kernel_launch(void* const* d_in, const int* in_sizes, int n_in,
                              void* d_out, int out_size, void* d_ws, size_t ws_size,
                              hipStream_t stream) {
  (void)out_size;
  const float* xin = (const float*)d_in[0];
  const float* Z = (const float*)d_in[1];
  const float* qmu = (const float*)d_in[2];
  const float* qsqrt = (const float*)d_in[3];
  const float* vptr = (const float*)d_in[4];
  const float* lptr = (const float*)d_in[5];
  {
    int scalars = 0;
    for (int i = 0; i < n_in; ++i) {
      if (in_sizes[i] == N_ * H_ * W_ * C_) xin = (const float*)d_in[i];
      else if (in_sizes[i] == G_ * M_ * L_) Z = (const float*)d_in[i];
      else if (in_sizes[i] == M_ * G_) qmu = (const float*)d_in[i];
      else if (in_sizes[i] == G_ * MM_) qsqrt = (const float*)d_in[i];
      else if (in_sizes[i] == 1) {
        if (scalars == 0) vptr = (const float*)d_in[i];
        else lptr = (const float*)d_in[i];
        ++scalars;
      }
    }
  }
  float* outp = (float*)d_out;

  auto align256 = [](size_t b) { return (b + 255) & ~(size_t)255; };
  size_t fixed = 0;
  fixed += align256((size_t)G_ * L_ * M_ * 4);      // Zt
  fixed += align256((size_t)G_ * M_ * 4);           // znorm
  fixed += align256((size_t)PN_ * LP_ * 4);         // pat
  fixed += align256((size_t)PN_ * 4);               // pnorm
  fixed += align256((size_t)G_ * MM_ * 4) * 2;      // Kuu32, Kinv32
  fixed += align256((size_t)G_ * 192 * 192 * 4);    // Ebuf
  fixed += align256((size_t)G_ * MM_ * 8);          // Kuu64
  fixed += align256((size_t)G_ * MM_ * 4) * 2;      // Xf, Rf (fp32 since r7)
  fixed += align256((size_t)G_ * MM_ * 2) * 2;      // Shi, Slo
  fixed += align256((size_t)G_ * M_ * 4);           // cvec
  size_t kfam = (size_t)G_ * PN_ * M_ * 8;          // Kx fp32 + Khi + Klo per full span
  int nc = 4;
  if (ws_size >= fixed + align256(kfam) + (1u << 20)) nc = 1;
  else if (ws_size >= fixed + align256(kfam / 2) + (1u << 20)) nc = 2;
  int chx = PN_ / nc;   // divisible by 128 for nc in {1,2,4}

  char* w = (char*)d_ws;
  auto alloc = [&](size_t bytes) {
    char* r = w;
    w += (bytes + 255) & ~(size_t)255;
    return r;
  };
  float* Zt      = (float*)alloc((size_t)G_ * L_ * M_ * 4);
  float* znorm   = (float*)alloc((size_t)G_ * M_ * 4);
  float* pat     = (float*)alloc((size_t)PN_ * LP_ * 4);
  float* pnorm   = (float*)alloc((size_t)PN_ * 4);
  float* Kuu32   = (float*)alloc((size_t)G_ * MM_ * 4);
  float* Kinv32  = (float*)alloc((size_t)G_ * MM_ * 4);
  float* Ebuf    = (float*)alloc((size_t)G_ * 192 * 192 * 4);
  double* Kuu64  = (double*)alloc((size_t)G_ * MM_ * 8);
  float* Xf      = (float*)alloc((size_t)G_ * MM_ * 4);
  float* Rf      = (float*)alloc((size_t)G_ * MM_ * 4);
  ushortt* Shi   = (ushortt*)alloc((size_t)G_ * MM_ * 2);
  ushortt* Slo   = (ushortt*)alloc((size_t)G_ * MM_ * 2);
  float* cvec    = (float*)alloc((size_t)G_ * M_ * 4);
  float* Kx      = (float*)alloc((size_t)G_ * chx * M_ * 4);
  ushortt* Khi   = (ushortt*)alloc((size_t)G_ * chx * M_ * 2);
  ushortt* Klo   = (ushortt*)alloc((size_t)G_ * chx * M_ * 2);

  int chx64 = chx / 64;
  int T = 12 * chx64;      // kufg tiles in chunk 0 (both g)
  int Th = T / 2;          // half fused with each inversion; Th/4 blocks

  // ---- merged prep: patchnorm + Zt/znorm/out-init + Kuu tiles ----
  k_prep<<<PNB_ + P1B_ + 288, 512, 0, stream>>>(
      xin, Z, vptr, lptr, Zt, znorm, outp, pat, pnorm, Kuu64, Kuu32);

  // ---- fp32 seed: Kinv32 via 2x2 block Schur (192+192); inversions fused
  //      with chunk-0 Kuf tiles (independent work on otherwise-idle CUs) ----
  k_invkufg<<<G_ + Th / 4, 1024, 0, stream>>>(
      Kuu32, Kinv32, pat, Zt, znorm, pnorm, vptr, lptr,
      Kx, Khi, Klo, 0, chx, 0);
  k_sgemm<<<dim3(6, 6, G_), 512, 0, stream>>>(
      Kinv32, M_, 0, MM_, Kuu32 + 192, M_, 0, 0, MM_,
      nullptr, 0, 0.0f, 1.0f, 0,
      Ebuf, 192, 192 * 192, nullptr, 0, 0, nullptr, nullptr, 192, 192, 192);
  k_sgemm<<<dim3(6, 6, G_), 512, 0, stream>>>(
      Kuu32 + 192, M_, 1, MM_, Ebuf, 192, 0, 0, 192 * 192,
      Kuu32 + 192 * M_ + 192, MM_, 1.0f, -1.0f, 0,
      Kuu32 + 192 * M_ + 192, M_, MM_, nullptr, 0, 0, nullptr, nullptr, 192, 192, 192);
  k_invkufg<<<G_ + Th / 4, 1024, 0, stream>>>(
      Kuu32 + 192 * M_ + 192, Kinv32 + 192 * M_ + 192, pat, Zt, znorm, pnorm,
      vptr, lptr, Kx, Khi, Klo, 0, chx, Th);
  k_sgemm<<<dim3(6, 6, G_), 512, 0, stream>>>(
      Ebuf, 192, 0, 192 * 192, Kinv32 + 192 * M_ + 192, M_, 0, 0, MM_,
      nullptr, 0, 0.0f, -1.0f, 0,
      Kinv32 + 192, M_, MM_, Kinv32 + 192 * M_, M_, MM_, nullptr, nullptr, 192, 192, 192);
  k_sgemm<<<dim3(6, 6, G_), 512, 0, stream>>>(
      Kinv32 + 192, M_, 0, MM_, Ebuf, 192, 1, 0, 192 * 192,
      Kinv32, MM_, 1.0f, -1.0f, 0,
      Kinv32, M_, MM_, nullptr, 0, 0, nullptr, nullptr, 192, 192, 192);

  // ---- Newton residual in fp64 (the only cancellation-critical GEMM):
  //      R = I - Kuu64*X0, output fp32 ----
  k_dgemmx<<<dim3(12, 12, G_), 512, 0, stream>>>(
      Kuu64, 1, M_, 0, (size_t)MM_,
      Kinv32, 0, M_, 0, 0, (size_t)MM_,
      nullptr, 0, 0, 0.0,
      -1.0, 1, nullptr, M_, (size_t)MM_, Rf, nullptr, nullptr, M_, M_, M_);
  // ---- X2 = X0 + X0*R : fp32 ----
  k_sgemm<<<dim3(12, 12, G_), 512, 0, stream>>>(
      Kinv32, M_, 0, MM_, Rf, M_, 0, 0, MM_,
      Kinv32, MM_, 1.0f, 1.0f, 0,
      Xf, M_, MM_, nullptr, 0, 0, nullptr, nullptr, M_, M_, M_);

  // ---- V = X2 * tril(Lq) : fp32 with exact-zero k-tile skip ----
  k_sgemm<<<dim3(12, 12, G_), 512, 0, stream>>>(
      Xf, M_, 0, MM_, qsqrt, M_, 0, 1, MM_,
      nullptr, 0, 0.0f, 1.0f, 0,
      Rf, M_, MM_, nullptr, 0, 0, nullptr, nullptr, M_, M_, M_);       // Rf = V
  // ---- S = V*V^T - X2 -> bf16 hi/lo; symmetric: lower tiles + mirror ----
  k_sgemm<<<dim3(12, 12, G_), 512, 0, stream>>>(
      Rf, M_, 0, MM_, Rf, M_, 1, 0, MM_,
      Xf, MM_, -1.0f, 1.0f, 0,
      nullptr, M_, MM_, nullptr, 0, 0, Shi, Slo, M_, M_, M_);
  k_cvec32<<<(G_ * M_ + 255) / 256, 256, 0, stream>>>(Xf, qmu, cvec);

  // ---- per-chunk: chunk 0's K already built by the fused kernels ----
  for (int ch = 0; ch < nc; ++ch) {
    int x0 = ch * chx;
    if (ch > 0)
      k_kufg<<<dim3(M_ / 64, chx / 64, G_), 256, 0, stream>>>(
          pat, Zt, znorm, pnorm, vptr, lptr, Kx, Khi, Klo, x0, chx);
    k_ufoldm<<<dim3(1, chx / 64, G_), 256, 0, stream>>>(
        Khi, Klo, Kx, Shi, Slo, cvec, vptr, outp, x0, chx);
  }
}

// Round 14
// 557.682 us; speedup vs baseline: 1.5842x; 1.5765x over previous
//
#include <hip/hip_runtime.h>
#include <hip/hip_bf16.h>

typedef unsigned short ushortt;
typedef __attribute__((ext_vector_type(8))) short short8v;
typedef __attribute__((ext_vector_type(4))) float f32x4;

#define H_ 32
#define W_ 32
#define C_ 3
#define PH_ 5
#define PW_ 5
#define HP_ 28
#define WP_ 28
#define P_ 784
#define N_ 32
#define L_ 75
#define LP_ 80            /* padded L for float4 staging */
#define G_ 2
#define M_ 384
#define MM_ (M_*M_)       /* 147456 */
#define PN_ (P_*N_)       /* 25088 */
#define JITTER_ 1e-6
#define PNB_ 3136         /* patchnorm blocks: PN_/8 */
#define P1B_ 113          /* prep1 blocks: ceil(G_*L_*M_/512) */

__device__ __forceinline__ float bf2f(ushortt u) {
  return __uint_as_float(((unsigned int)u) << 16);
}
__device__ __forceinline__ ushortt f2bf(float f) {
  __hip_bfloat16 h = __float2bfloat16(f);
  ushortt u;
  __builtin_memcpy(&u, &h, sizeof(u));
  return u;
}

// accurate exp(t) for t <= 0, fp64
__device__ __forceinline__ double exp64(double t) {
  double y = t * 1.4426950408889634;
  double nn = rint(y);
  double z = (y - nn) * 0.6931471805599453;
  double e = 1.6059043836821613e-10;
  e = fma(e, z, 2.08767569878681e-9);
  e = fma(e, z, 2.505210838544172e-8);
  e = fma(e, z, 2.755731922398589e-7);
  e = fma(e, z, 2.7557319223985893e-6);
  e = fma(e, z, 2.48015873015873e-5);
  e = fma(e, z, 1.984126984126984e-4);
  e = fma(e, z, 1.3888888888888889e-3);
  e = fma(e, z, 8.333333333333333e-3);
  e = fma(e, z, 4.1666666666666664e-2);
  e = fma(e, z, 1.6666666666666666e-1);
  e = fma(e, z, 0.5);
  e = fma(e, z, 1.0);
  e = fma(e, z, 1.0);
  return ldexp(e, (int)nn);
}

// ================= merged prep: patchnorm (blocks 0..PNB_-1),
//                   Zt/znorm/out-init (next P1B_), Kuu tiles (last 288) ======
__global__ __launch_bounds__(512) void k_prep(
    const float* __restrict__ xin, const float* __restrict__ Z,
    const float* vptr, const float* lptr,
    float* __restrict__ Zt, float* __restrict__ znorm,
    float* __restrict__ outp, float* __restrict__ pat,
    float* __restrict__ pnorm,
    double* __restrict__ Kuu64, float* __restrict__ Kuu32) {
  int b = blockIdx.x;
  if (b < PNB_) {
    // ---- patchnorm: 8 waves/block, one wave per x ----
    int wv = threadIdx.x >> 6;
    int t = threadIdx.x & 63;
    int x = b * 8 + wv;
    int n = x & 31, p = x >> 5;
    int hp = p / WP_, wp = p % WP_;
    const float* xb = xin + n * (H_ * W_ * C_);
    auto pval = [&](int l) -> float {
      if (l >= L_) return 0.f;
      int q = l / C_, c = l % C_;
      int i = q / PW_, j = q % PW_;
      return xb[((hp + i) * W_ + (wp + j)) * C_ + c];
    };
    float v1 = pval(t);
    float v2 = (t < 16) ? pval(t + 64) : 0.f;
    pat[(size_t)x * LP_ + t] = v1;
    if (t < 16) pat[(size_t)x * LP_ + 64 + t] = v2;
    float s = v1 * v1 + v2 * v2;
#pragma unroll
    for (int off = 32; off; off >>= 1) s += __shfl_down(s, off);
    if (t == 0) pnorm[x] = s;
    return;
  }
  if (b < PNB_ + P1B_) {
    // ---- Zt transpose + znorm + output init ----
    int idx = (b - PNB_) * 512 + threadIdx.x;
    if (idx < G_ * L_ * M_) {
      int m = idx % M_;
      int l = (idx / M_) % L_;
      int g = idx / (M_ * L_);
      Zt[idx] = Z[(g * M_ + m) * L_ + l];
    }
    if (idx < G_ * M_) {
      const float* zr = Z + (size_t)idx * L_;
      float s = 0.f;
      for (int l = 0; l < L_; ++l) s = fmaf(zr[l], zr[l], s);
      znorm[idx] = s;
    }
    if (idx < PN_ * G_) {
      outp[idx] = 0.f;
      outp[PN_ * G_ + idx] = vptr[0];
    }
    return;
  }
  // ---- Kuu fp64 + fp32 copy: tiled, 32x32 per block ----
  int q = b - PNB_ - P1B_;
  int bx = q % 12, by = (q / 12) % 12, g = q / 144;
  int row0 = by * 32, col0 = bx * 32;
  __shared__ float Zr[32][76], Zc[32][76];
  int t = threadIdx.x;
  for (int idx = t; idx < 2400; idx += 512) {
    int r = idx / 75, l = idx % 75;
    Zr[r][l] = Z[((size_t)(g * M_ + row0 + r)) * L_ + l];
    Zc[r][l] = Z[((size_t)(g * M_ + col0 + r)) * L_ + l];
  }
  __syncthreads();

  int ty = t >> 4, tx = t & 15;
  double s0 = 0.0, s1 = 0.0;
#pragma unroll 5
  for (int l = 0; l < 75; ++l) {
    double zi = (double)Zr[ty][l];
    double d0 = zi - (double)Zc[tx][l];
    double d1 = zi - (double)Zc[tx + 16][l];
    s0 = fma(d0, d0, s0);
    s1 = fma(d1, d1, s1);
  }
  double v = (double)vptr[0], ls = (double)lptr[0];
  double inv2 = -0.5 / (ls * ls);
  int r = row0 + ty;
  double ss[2] = {s0, s1};
#pragma unroll
  for (int cc = 0; cc < 2; ++cc) {
    int j = col0 + tx + cc * 16;
    double val = v * exp64(ss[cc] * inv2);
    if (r == j) val += JITTER_;
    size_t o = (size_t)g * MM_ + (size_t)r * M_ + j;
    Kuu64[o] = val;
    Kuu32[o] = (float)val;
  }
}

// ================= fused: 192x192 blocked GJ inverse (blocks 0..1) =================
// ================= + Kuf-build tiles (blocks 2..)                  =================
// r8-verified structure (measured 104-105us/dispatch): Pinv via LDS,
// single-wave phase 2. (r9's all-wave redundant shuffle inversion regressed
// to 145us: __shfl = ds_bpermute = LDS pipe; 16x traffic.)
__global__ __launch_bounds__(1024, 1) void k_invkufg(
    const float* __restrict__ Ain, float* __restrict__ Aout,
    const float* __restrict__ pat, const float* __restrict__ Zt,
    const float* __restrict__ znorm, const float* __restrict__ pnorm,
    const float* vptr, const float* lptr,
    float* __restrict__ Kx, ushortt* __restrict__ Khi, ushortt* __restrict__ Klo,
    int x0, int chx, int tile0) {
  __shared__ __align__(16) char smem[37888];

  if (blockIdx.x < G_) {
    // ---------------- inversion path ----------------
    __builtin_amdgcn_s_setprio(1);
    float (*rowb)[192]  = (float(*)[192])(smem);           // pivot-row panel R
    float (*rowb2)[192] = (float(*)[192])(smem + 12288);   // R' = Pinv * R
    float (*colbT)[192] = (float(*)[192])(smem + 24576);   // colbT[k][i]
    float (*Pinv)[16]   = (float(*)[16])(smem + 36864);

    int g = blockIdx.x;
    const float* A = Ain + (size_t)g * MM_;
    float* O = Aout + (size_t)g * MM_;
    int t = threadIdx.x;
    int rid = t >> 5, cid = t & 31;
    int r0 = rid * 6, c0 = cid * 6;

    float a[6][6];
#pragma unroll
    for (int ii = 0; ii < 6; ++ii) {
#pragma unroll
      for (int j2 = 0; j2 < 3; ++j2) {
        float2 v = *(const float2*)&A[(size_t)(r0 + ii) * M_ + c0 + j2 * 2];
        a[ii][j2 * 2 + 0] = v.x; a[ii][j2 * 2 + 1] = v.y;
      }
    }

    for (int bs = 0; bs < 12; ++bs) {
      int kp = bs * 16;
      // ---- phase 1: publish panels from registers ----
#pragma unroll
      for (int ii = 0; ii < 6; ++ii) {
        int k = r0 + ii - kp;
        if ((unsigned)k < 16u) {
#pragma unroll
          for (int jj = 0; jj < 6; ++jj) rowb[k][c0 + jj] = a[ii][jj];
        }
      }
#pragma unroll
      for (int jj = 0; jj < 6; ++jj) {
        int c = c0 + jj - kp;
        if ((unsigned)c < 16u) {
#pragma unroll
          for (int ii = 0; ii < 6; ++ii) colbT[c][r0 + ii] = a[ii][jj];
        }
      }
      __syncthreads();

      // ---- phase 2: wave 0 inverts 16x16 pivot block in registers ----
      if (t < 64) {
        int r = t >> 2, cg = t & 3;
        float vals[4];
#pragma unroll
        for (int j = 0; j < 4; ++j) vals[j] = rowb[r][kp + cg * 4 + j];
#pragma unroll
        for (int k = 0; k < 16; ++k) {
          const int cgk = k >> 2, jk = k & 3;
          float pkk = __shfl(vals[jk], k * 4 + cgk);
          float c_ = __shfl(vals[jk], (t & 0x3c) | cgk);
          float p = 1.0f / pkk;
          float cp = c_ * p;
          bool pivRow = (r == k);
#pragma unroll
          for (int j = 0; j < 4; ++j) {
            float prj = __shfl(vals[j], k * 4 + cg);
            bool pivCol = (cg == cgk) && (j == jk);
            float gen = fmaf(-cp, prj, vals[j]);
            float nv = pivRow ? (pivCol ? p : p * prj)
                              : (pivCol ? -cp : gen);
            vals[j] = nv;
          }
        }
#pragma unroll
        for (int j = 0; j < 4; ++j) Pinv[r][cg * 4 + j] = vals[j];
      }
      __syncthreads();

      // ---- phase 3: rowb2 <- Pinv * rowb, all 1024 threads ----
      {
        int r = t >> 6;
        float pv[16];
#pragma unroll
        for (int m = 0; m < 16; ++m) pv[m] = Pinv[r][m];
#pragma unroll
        for (int rep = 0; rep < 3; ++rep) {
          int c = (t & 63) + 64 * rep;
          int cc = c - kp;
          float s;
          if ((unsigned)cc < 16u) {
            s = pv[cc];
          } else {
            s = 0.f;
#pragma unroll
            for (int m = 0; m < 16; ++m) s = fmaf(pv[m], rowb[m][c], s);
          }
          rowb2[r][c] = s;
        }
      }
      __syncthreads();

      // ---- phase 4: rank-16 update (bounded unroll: no spill) ----
#pragma unroll
      for (int jj = 0; jj < 6; ++jj) {
        int c = c0 + jj - kp;
        if ((unsigned)c < 16u) {
#pragma unroll
          for (int ii = 0; ii < 6; ++ii) a[ii][jj] = 0.f;
        }
      }
#pragma unroll 2
      for (int k = 0; k < 16; ++k) {
        float rk[6], ck[6];
#pragma unroll
        for (int j2 = 0; j2 < 3; ++j2) {
          float2 v = *(const float2*)&rowb2[k][c0 + j2 * 2];
          rk[j2 * 2 + 0] = v.x; rk[j2 * 2 + 1] = v.y;
        }
#pragma unroll
        for (int i2 = 0; i2 < 3; ++i2) {
          float2 v = *(const float2*)&colbT[k][r0 + i2 * 2];
          ck[i2 * 2 + 0] = v.x; ck[i2 * 2 + 1] = v.y;
        }
#pragma unroll
        for (int ii = 0; ii < 6; ++ii)
#pragma unroll
          for (int jj = 0; jj < 6; ++jj)
            a[ii][jj] = fmaf(-ck[ii], rk[jj], a[ii][jj]);
      }
      // pivot rows: overwrite with R'
#pragma unroll
      for (int ii = 0; ii < 6; ++ii) {
        int k = r0 + ii - kp;
        if ((unsigned)k < 16u) {
#pragma unroll
          for (int jj = 0; jj < 6; ++jj) a[ii][jj] = rowb2[k][c0 + jj];
        }
      }
      __syncthreads();
    }

#pragma unroll
    for (int ii = 0; ii < 6; ++ii) {
#pragma unroll
      for (int j2 = 0; j2 < 3; ++j2) {
        float2 v = {a[ii][j2 * 2 + 0], a[ii][j2 * 2 + 1]};
        *(float2*)&O[(size_t)(r0 + ii) * M_ + c0 + j2 * 2] = v;
      }
    }
    return;
  }

  // ---------------- kufg path: 4 groups x one 64x64 tile ----------------
  typedef float lds68[16][68];
  lds68* As = (lds68*)(smem);            // As[grp][k][r]
  lds68* Bs = (lds68*)(smem + 17408);    // Bs[grp][k][c]

  int bid = (int)blockIdx.x - G_;
  int grp = threadIdx.x >> 8;
  int t = threadIdx.x & 255;
  int tile = tile0 + bid * 4 + grp;
  int chx64 = chx >> 6;
  int col = tile % 6;
  int rg = tile / 6;
  int g = rg / chx64;
  int row = rg % chx64;
  int col0 = col * 64;
  int row0 = row * 64;
  int tr = t >> 4, tc = t & 15;
  float acc[4][4] = {};

  for (int kt = 0; kt < LP_; kt += 16) {
    {
      int r = t >> 2, k4 = (t & 3) * 4;
      float4 av = *(const float4*)&pat[(size_t)(x0 + row0 + r) * LP_ + kt + k4];
      As[grp][k4 + 0][r] = av.x;
      As[grp][k4 + 1][r] = av.y;
      As[grp][k4 + 2][r] = av.z;
      As[grp][k4 + 3][r] = av.w;
    }
    {
      int k = t >> 4, c4 = (t & 15) * 4;
      float4 bv = {0.f, 0.f, 0.f, 0.f};
      if (kt + k < L_)
        bv = *(const float4*)&Zt[((size_t)(g * L_ + kt + k)) * M_ + col0 + c4];
      *(float4*)&Bs[grp][k][c4] = bv;
    }
    __syncthreads();
#pragma unroll 4
    for (int k = 0; k < 16; ++k) {
      float4 av = *(const float4*)&As[grp][k][tr * 4];
      float4 bv = *(const float4*)&Bs[grp][k][tc * 4];
      float a4[4] = {av.x, av.y, av.z, av.w};
      float b4[4] = {bv.x, bv.y, bv.z, bv.w};
#pragma unroll
      for (int i = 0; i < 4; ++i)
#pragma unroll
        for (int j = 0; j < 4; ++j) acc[i][j] = fmaf(a4[i], b4[j], acc[i][j]);
    }
    __syncthreads();
  }
  float v = vptr[0], ls = lptr[0];
  float c2 = -0.72134752044f / (ls * ls);
#pragma unroll
  for (int i = 0; i < 4; ++i) {
    int xl = row0 + tr * 4 + i;
    float pn = pnorm[x0 + xl];
    float tmp[4];
    ushortt hi[4], lo[4];
#pragma unroll
    for (int j = 0; j < 4; ++j) {
      int m = col0 + tc * 4 + j;
      float sq = znorm[g * M_ + m] + pn - 2.0f * acc[i][j];
      tmp[j] = v * exp2f(sq * c2);
      hi[j] = f2bf(tmp[j]);
      lo[j] = f2bf(tmp[j] - bf2f(hi[j]));
    }
    size_t base = ((size_t)g * chx + xl) * M_ + col0 + tc * 4;
    float4 ov = {tmp[0], tmp[1], tmp[2], tmp[3]};
    *(float4*)&Kx[base] = ov;
    *(ushort4*)&Khi[base] = make_ushort4(hi[0], hi[1], hi[2], hi[3]);
    *(ushort4*)&Klo[base] = make_ushort4(lo[0], lo[1], lo[2], lo[3]);
  }
}

// ---------------- fp32 tiled GEMM ----------------
__global__ __launch_bounds__(512) void k_sgemm(
    const float* __restrict__ A, int lda, int tA, int sAg,
    const float* __restrict__ B, int ldb, int tB, int btril, int sBg,
    const float* __restrict__ Cin, int sCing, float beta,
    float alpha, int addI,
    float* __restrict__ Cout, int ldc, int sCg,
    float* __restrict__ CoutT, int ldt, int sTg,
    ushortt* __restrict__ shiOut, ushortt* __restrict__ sloOut,
    int M, int N, int K) {
  int g = blockIdx.z;
  int row0 = blockIdx.y * 32, col0 = blockIdx.x * 32;
  if (shiOut && col0 > row0) return;   // symmetric output: lower tiles only
  A += (size_t)g * sAg;
  B += (size_t)g * sBg;
  if (Cin) Cin += (size_t)g * sCing;
  if (Cout) Cout += (size_t)g * sCg;
  if (CoutT) CoutT += (size_t)g * sTg;
  if (shiOut) { shiOut += (size_t)g * sCg; sloOut += (size_t)g * sCg; }

  __shared__ __align__(16) float As[32][34], Bs[32][34];
  int t = threadIdx.x;
  int tx = t & 15, ty = t >> 4;
  float acc0 = 0.f, acc1 = 0.f;

  int kt0 = btril ? (col0 & ~31) : 0;  // tiles fully above tril are exact zeros
  for (int kt = kt0; kt < K; kt += 32) {
    for (int idx = t; idx < 1024; idx += 512) {
      int rr = idx >> 5, cc = idx & 31;
      {
        int gr = row0 + rr, gk = kt + cc;
        As[rr][cc] = tA ? A[(size_t)gk * lda + gr] : A[(size_t)gr * lda + gk];
      }
      {
        int gk = kt + rr, gc = col0 + cc;
        float bv = tB ? B[(size_t)gc * ldb + gk] : B[(size_t)gk * ldb + gc];
        if (btril && gc > gk) bv = 0.f;
        Bs[rr][cc] = bv;
      }
    }
    __syncthreads();
#pragma unroll 8
    for (int kk = 0; kk < 32; ++kk) {
      float a0 = As[ty][kk];
      float2 b = *(const float2*)&Bs[kk][tx * 2];
      acc0 = fmaf(a0, b.x, acc0);
      acc1 = fmaf(a0, b.y, acc1);
    }
    __syncthreads();
  }
  float accs[2] = {acc0, acc1};
#pragma unroll
  for (int b2 = 0; b2 < 2; ++b2) {
    int gr = row0 + ty, gc = col0 + tx * 2 + b2;
    float val = alpha * accs[b2];
    if (addI && gr == gc) val += 1.0f;
    if (Cin) val += beta * Cin[(size_t)gr * ldc + gc];
    if (Cout) Cout[(size_t)gr * ldc + gc] = val;
    if (CoutT) CoutT[(size_t)gc * ldt + gr] = val;
    if (shiOut) {
      ushortt h = f2bf(val);
      shiOut[(size_t)gr * ldc + gc] = h;
      sloOut[(size_t)gr * ldc + gc] = f2bf(val - bf2f(h));
      // mirror: acc symmetric; use transposed Cin element for exactness
      float vm = alpha * accs[b2];
      if (Cin) vm += beta * Cin[(size_t)gc * ldc + gr];
      ushortt hm = f2bf(vm);
      shiOut[(size_t)gc * ldc + gr] = hm;
      sloOut[(size_t)gc * ldc + gr] = f2bf(vm - bf2f(hm));
    }
  }
}

// ---------------- mixed-precision fp64-accum GEMM (Newton residual only) ----------------
__global__ __launch_bounds__(512) void k_dgemmx(
    const void* __restrict__ Ap, int aF64, int lda, int tA, size_t sAg,
    const void* __restrict__ Bp, int bF64, int ldb, int tB, int btril, size_t sBg,
    const void* __restrict__ Cp, int cF64, size_t sCing, double beta,
    double alpha, int addI,
    double* __restrict__ Cout, int ldc, size_t sCg,
    float* __restrict__ f32out,
    ushortt* __restrict__ shiOut, ushortt* __restrict__ sloOut,
    int M, int N, int K) {
  int g = blockIdx.z;
  const double* A64 = (const double*)Ap + (size_t)g * sAg;
  const float* A32 = (const float*)Ap + (size_t)g * sAg;
  const double* B64 = (const double*)Bp + (size_t)g * sBg;
  const float* B32 = (const float*)Bp + (size_t)g * sBg;
  const double* C64 = Cp ? (const double*)Cp + (size_t)g * sCing : nullptr;
  const float* C32 = Cp ? (const float*)Cp + (size_t)g * sCing : nullptr;
  if (Cout) Cout += (size_t)g * sCg;
  if (f32out) f32out += (size_t)g * sCg;
  if (shiOut) shiOut += (size_t)g * sCg;
  if (sloOut) sloOut += (size_t)g * sCg;

  __shared__ __align__(16) double As[32][34], Bs[32][34];
  int t = threadIdx.x;
  int tx = t & 15, ty = t >> 4;
  int row0 = blockIdx.y * 32, col0 = blockIdx.x * 32;
  double acc0 = 0., acc1 = 0.;

  for (int kt = 0; kt < K; kt += 32) {
    for (int idx = t; idx < 1024; idx += 512) {
      int rr = idx >> 5, cc = idx & 31;
      {
        int gr = row0 + rr, gk = kt + cc;
        size_t ai = tA ? ((size_t)gk * lda + gr) : ((size_t)gr * lda + gk);
        As[rr][cc] = aF64 ? A64[ai] : (double)A32[ai];
      }
      {
        int gk = kt + rr, gc = col0 + cc;
        size_t bi = tB ? ((size_t)gc * ldb + gk) : ((size_t)gk * ldb + gc);
        double bv = bF64 ? B64[bi] : (double)B32[bi];
        if (btril && gc > gk) bv = 0.0;
        Bs[rr][cc] = bv;
      }
    }
    __syncthreads();
#pragma unroll 8
    for (int kk = 0; kk < 32; ++kk) {
      double a0 = As[ty][kk];
      double2 b = *(const double2*)&Bs[kk][tx * 2];
      acc0 = fma(a0, b.x, acc0);
      acc1 = fma(a0, b.y, acc1);
    }
    __syncthreads();
  }
  double accs[2] = {acc0, acc1};
#pragma unroll
  for (int b2 = 0; b2 < 2; ++b2) {
    int gr = row0 + ty, gc = col0 + tx * 2 + b2;
    double val = alpha * accs[b2];
    if (addI && gr == gc) val += 1.0;
    if (C64) {
      double cv = cF64 ? C64[(size_t)gr * ldc + gc] : (double)C32[(size_t)gr * ldc + gc];
      val += beta * cv;
    }
    if (Cout) Cout[(size_t)gr * ldc + gc] = val;
    if (f32out) f32out[(size_t)gr * ldc + gc] = (float)val;
    if (shiOut) {
      float sv = (float)val;
      ushortt h = f2bf(sv);
      shiOut[(size_t)gr * ldc + gc] = h;
      sloOut[(size_t)gr * ldc + gc] = f2bf(sv - bf2f(h));
    }
  }
}

// ---------------- c_g = X * q_mu[:,g]  (fp32 X, fp64 accum) ----------------
__global__ void k_cvec32(const float* __restrict__ X, const float* __restrict__ qmu,
                         float* __restrict__ cvec) {
  int idx = blockIdx.x * 256 + threadIdx.x;
  if (idx >= G_ * M_) return;
  int m = idx % M_, g = idx / M_;
  const float* row = X + (size_t)g * MM_ + (size_t)m * M_;
  double s = 0.0;
  for (int k = 0; k < M_; ++k) s = fma((double)row[k], (double)qmu[k * G_ + g], s);
  cvec[idx] = (float)s;
}

// ---------------- Kuf as GEMM (64x64 tile) -> Kx fp32 + Khi/Klo bf16 ----------------
// (standalone version, used for chunks >= 1 when nc > 1)
__global__ __launch_bounds__(256) void k_kufg(const float* __restrict__ pat,
                                              const float* __restrict__ Zt,
                                              const float* __restrict__ znorm,
                                              const float* __restrict__ pnorm,
                                              const float* vptr, const float* lptr,
                                              float* __restrict__ Kx,
                                              ushortt* __restrict__ Khi,
                                              ushortt* __restrict__ Klo,
                                              int x0, int chx) {
  int g = blockIdx.z;
  int col0 = blockIdx.x * 64;
  int row0 = blockIdx.y * 64;
  __shared__ __align__(16) float As[16][68];
  __shared__ __align__(16) float Bs[16][68];
  int t = threadIdx.x;
  int tr = t >> 4, tc = t & 15;
  float acc[4][4] = {};

  for (int kt = 0; kt < LP_; kt += 16) {
    {
      int r = t >> 2, k4 = (t & 3) * 4;
      float4 av = *(const float4*)&pat[(size_t)(x0 + row0 + r) * LP_ + kt + k4];
      As[k4 + 0][r] = av.x;
      As[k4 + 1][r] = av.y;
      As[k4 + 2][r] = av.z;
      As[k4 + 3][r] = av.w;
    }
    {
      int k = t >> 4, c4 = (t & 15) * 4;
      float4 bv = {0.f, 0.f, 0.f, 0.f};
      if (kt + k < L_)
        bv = *(const float4*)&Zt[((size_t)(g * L_ + kt + k)) * M_ + col0 + c4];
      *(float4*)&Bs[k][c4] = bv;
    }
    __syncthreads();
#pragma unroll
    for (int k = 0; k < 16; ++k) {
      float4 av = *(const float4*)&As[k][tr * 4];
      float4 bv = *(const float4*)&Bs[k][tc * 4];
      float a4[4] = {av.x, av.y, av.z, av.w};
      float b4[4] = {bv.x, bv.y, bv.z, bv.w};
#pragma unroll
      for (int i = 0; i < 4; ++i)
#pragma unroll
        for (int j = 0; j < 4; ++j) acc[i][j] = fmaf(a4[i], b4[j], acc[i][j]);
    }
    __syncthreads();
  }
  float v = vptr[0], ls = lptr[0];
  float c2 = -0.72134752044f / (ls * ls);
#pragma unroll
  for (int i = 0; i < 4; ++i) {
    int xl = row0 + tr * 4 + i;
    float pn = pnorm[x0 + xl];
    float tmp[4];
    ushortt hi[4], lo[4];
#pragma unroll
    for (int j = 0; j < 4; ++j) {
      int m = col0 + tc * 4 + j;
      float sq = znorm[g * M_ + m] + pn - 2.0f * acc[i][j];
      tmp[j] = v * exp2f(sq * c2);
      hi[j] = f2bf(tmp[j]);
      lo[j] = f2bf(tmp[j] - bf2f(hi[j]));
    }
    size_t base = ((size_t)g * chx + xl) * M_ + col0 + tc * 4;
    float4 ov = {tmp[0], tmp[1], tmp[2], tmp[3]};
    *(float4*)&Kx[base] = ov;
    *(ushort4*)&Khi[base] = make_ushort4(hi[0], hi[1], hi[2], hi[3]);
    *(ushort4*)&Klo[base] = make_ushort4(lo[0], lo[1], lo[2], lo[3]);
  }
}

// ---------------- LDS frag helper: 16B-aligned read -> short8v ----------------
__device__ __forceinline__ short8v lds_frag(const ushortt* p) {
  int4 v = *(const int4*)p;
  short8v r;
  __builtin_memcpy(&r, &v, 16);
  return r;
}

// ---------------- MFMA U-GEMM + fold, LDS-staged ----------------
// r14: UNCONDITIONAL REVERT to the r8-proven 128x128 version (atomics,
// acc[2][8] = 64 VGPRs). r12 (acc[24]) and r13 (acc[12]+fp64 partials)
// both spilled: this compiler caps 256-thread kernels at ~64-90 VGPR
// regardless of demand, and launch_bounds has not raised it. 64 VGPRs of
// live accumulator is the viable boundary.
#define STR_ 40
__global__ __launch_bounds__(256) void k_ufoldm(
    const ushortt* __restrict__ Khi, const ushortt* __restrict__ Klo,
    const float* __restrict__ Kx32,
    const ushortt* __restrict__ Shi, const ushortt* __restrict__ Slo,
    const float* __restrict__ cvec, float* __restrict__ outp,
    int x0, int chx) {
  int g = blockIdx.z;
  int col0 = blockIdx.x * 128;
  int row0 = blockIdx.y * 128;
  const ushortt* Ahg = Khi + (size_t)g * chx * M_;
  const ushortt* Alg = Klo + (size_t)g * chx * M_;
  const float* A32 = Kx32 + (size_t)g * chx * M_;
  const ushortt* Bhg = Shi + (size_t)g * MM_;
  const ushortt* Blg = Slo + (size_t)g * MM_;

  __shared__ __align__(16) ushortt Ahs[128][STR_], Als[128][STR_];
  __shared__ __align__(16) ushortt Bhs[128][STR_], Bls[128][STR_];
  __shared__ float cs[128];

  int t = threadIdx.x;
  if (t < 128) cs[t] = cvec[g * M_ + col0 + t];

  int w = t >> 6, lane = t & 63, n15 = lane & 15, q = lane >> 4;
  int q8 = q * 8;

  int sr = t >> 1, sk = (t & 1) * 16;

  f32x4 acc[2][8];
#pragma unroll
  for (int rf = 0; rf < 2; ++rf)
#pragma unroll
    for (int ct = 0; ct < 8; ++ct) acc[rf][ct] = (f32x4){0.f, 0.f, 0.f, 0.f};

  for (int kt = 0; kt < M_; kt += 32) {
    {
      size_t abase = (size_t)(row0 + sr) * M_ + kt + sk;
      uint4 a0 = *(const uint4*)&Ahg[abase];
      uint4 a1 = *(const uint4*)&Ahg[abase + 8];
      *(uint4*)&Ahs[sr][sk] = a0;
      *(uint4*)&Ahs[sr][sk + 8] = a1;
      uint4 b0 = *(const uint4*)&Alg[abase];
      uint4 b1 = *(const uint4*)&Alg[abase + 8];
      *(uint4*)&Als[sr][sk] = b0;
      *(uint4*)&Als[sr][sk + 8] = b1;
      size_t bbase = (size_t)(col0 + sr) * M_ + kt + sk;
      uint4 c0 = *(const uint4*)&Bhg[bbase];
      uint4 c1 = *(const uint4*)&Bhg[bbase + 8];
      *(uint4*)&Bhs[sr][sk] = c0;
      *(uint4*)&Bhs[sr][sk + 8] = c1;
      uint4 d0 = *(const uint4*)&Blg[bbase];
      uint4 d1 = *(const uint4*)&Blg[bbase + 8];
      *(uint4*)&Bls[sr][sk] = d0;
      *(uint4*)&Bls[sr][sk + 8] = d1;
    }
    __syncthreads();

    short8v ahi0 = lds_frag(&Ahs[w * 32 + n15][q8]);
    short8v ahi1 = lds_frag(&Ahs[w * 32 + 16 + n15][q8]);
    short8v alo0 = lds_frag(&Als[w * 32 + n15][q8]);
    short8v alo1 = lds_frag(&Als[w * 32 + 16 + n15][q8]);
#pragma unroll
    for (int ct = 0; ct < 8; ++ct) {
      short8v bhi = lds_frag(&Bhs[ct * 16 + n15][q8]);
      short8v blo = lds_frag(&Bls[ct * 16 + n15][q8]);
      acc[0][ct] = __builtin_amdgcn_mfma_f32_16x16x32_bf16(ahi0, bhi, acc[0][ct], 0, 0, 0);
      acc[0][ct] = __builtin_amdgcn_mfma_f32_16x16x32_bf16(ahi0, blo, acc[0][ct], 0, 0, 0);
      acc[0][ct] = __builtin_amdgcn_mfma_f32_16x16x32_bf16(alo0, bhi, acc[0][ct], 0, 0, 0);
      acc[1][ct] = __builtin_amdgcn_mfma_f32_16x16x32_bf16(ahi1, bhi, acc[1][ct], 0, 0, 0);
      acc[1][ct] = __builtin_amdgcn_mfma_f32_16x16x32_bf16(ahi1, blo, acc[1][ct], 0, 0, 0);
      acc[1][ct] = __builtin_amdgcn_mfma_f32_16x16x32_bf16(alo1, bhi, acc[1][ct], 0, 0, 0);
    }
    __syncthreads();
  }

  // fold: partial over cols [col0, col0+128). exact fp32 k, fp64 partials, atomics.
#pragma unroll
  for (int rf = 0; rf < 2; ++rf) {
#pragma unroll
    for (int reg = 0; reg < 4; ++reg) {
      int xr2 = row0 + w * 32 + rf * 16 + q * 4 + reg;
      const float* arow = &A32[(size_t)xr2 * M_ + col0];
      double pv = 0.0, pm = 0.0;
#pragma unroll
      for (int ct = 0; ct < 8; ++ct) {
        int col = ct * 16 + n15;
        float kval = arow[col];
        pv += (double)kval * acc[rf][ct][reg];
        pm += (double)kval * cs[col];
      }
#pragma unroll
      for (int mk = 1; mk < 16; mk <<= 1) {
        pv += __shfl_xor(pv, mk, 16);
        pm += __shfl_xor(pm, mk, 16);
      }
      if (n15 == 0) {
        int x = x0 + xr2;
        int p = x >> 5, n = x & 31;
        int oidx = n * (P_ * G_) + p * G_ + g;
        atomicAdd(&outp[oidx], (float)pm);
        atomicAdd(&outp[PN_ * G_ + oidx], (float)pv);
      }
    }
  }
}

extern "C" void kernel_launch(void* const* d_in, const int* in_sizes, int n_in,
                              void* d_out, int out_size, void* d_ws, size_t ws_size,
                              hipStream_t stream) {
  (void)out_size;
  const float* xin = (const float*)d_in[0];
  const float* Z = (const float*)d_in[1];
  const float* qmu = (const float*)d_in[2];
  const float* qsqrt = (const float*)d_in[3];
  const float* vptr = (const float*)d_in[4];
  const float* lptr = (const float*)d_in[5];
  {
    int scalars = 0;
    for (int i = 0; i < n_in; ++i) {
      if (in_sizes[i] == N_ * H_ * W_ * C_) xin = (const float*)d_in[i];
      else if (in_sizes[i] == G_ * M_ * L_) Z = (const float*)d_in[i];
      else if (in_sizes[i] == M_ * G_) qmu = (const float*)d_in[i];
      else if (in_sizes[i] == G_ * MM_) qsqrt = (const float*)d_in[i];
      else if (in_sizes[i] == 1) {
        if (scalars == 0) vptr = (const float*)d_in[i];
        else lptr = (const float*)d_in[i];
        ++scalars;
      }
    }
  }
  float* outp = (float*)d_out;

  auto align256 = [](size_t b) { return (b + 255) & ~(size_t)255; };
  size_t fixed = 0;
  fixed += align256((size_t)G_ * L_ * M_ * 4);      // Zt
  fixed += align256((size_t)G_ * M_ * 4);           // znorm
  fixed += align256((size_t)PN_ * LP_ * 4);         // pat
  fixed += align256((size_t)PN_ * 4);               // pnorm
  fixed += align256((size_t)G_ * MM_ * 4) * 2;      // Kuu32, Kinv32
  fixed += align256((size_t)G_ * 192 * 192 * 4);    // Ebuf
  fixed += align256((size_t)G_ * MM_ * 8);          // Kuu64
  fixed += align256((size_t)G_ * MM_ * 4) * 2;      // Xf, Rf (fp32 since r7)
  fixed += align256((size_t)G_ * MM_ * 2) * 2;      // Shi, Slo
  fixed += align256((size_t)G_ * M_ * 4);           // cvec
  size_t kfam = (size_t)G_ * PN_ * M_ * 8;          // Kx fp32 + Khi + Klo per full span
  int nc = 4;
  if (ws_size >= fixed + align256(kfam) + (1u << 20)) nc = 1;
  else if (ws_size >= fixed + align256(kfam / 2) + (1u << 20)) nc = 2;
  int chx = PN_ / nc;   // divisible by 128 for nc in {1,2,4}

  char* w = (char*)d_ws;
  auto alloc = [&](size_t bytes) {
    char* r = w;
    w += (bytes + 255) & ~(size_t)255;
    return r;
  };
  float* Zt      = (float*)alloc((size_t)G_ * L_ * M_ * 4);
  float* znorm   = (float*)alloc((size_t)G_ * M_ * 4);
  float* pat     = (float*)alloc((size_t)PN_ * LP_ * 4);
  float* pnorm   = (float*)alloc((size_t)PN_ * 4);
  float* Kuu32   = (float*)alloc((size_t)G_ * MM_ * 4);
  float* Kinv32  = (float*)alloc((size_t)G_ * MM_ * 4);
  float* Ebuf    = (float*)alloc((size_t)G_ * 192 * 192 * 4);
  double* Kuu64  = (double*)alloc((size_t)G_ * MM_ * 8);
  float* Xf      = (float*)alloc((size_t)G_ * MM_ * 4);
  float* Rf      = (float*)alloc((size_t)G_ * MM_ * 4);
  ushortt* Shi   = (ushortt*)alloc((size_t)G_ * MM_ * 2);
  ushortt* Slo   = (ushortt*)alloc((size_t)G_ * MM_ * 2);
  float* cvec    = (float*)alloc((size_t)G_ * M_ * 4);
  float* Kx      = (float*)alloc((size_t)G_ * chx * M_ * 4);
  ushortt* Khi   = (ushortt*)alloc((size_t)G_ * chx * M_ * 2);
  ushortt* Klo   = (ushortt*)alloc((size_t)G_ * chx * M_ * 2);

  int chx64 = chx / 64;
  int T = 12 * chx64;      // kufg tiles in chunk 0 (both g)
  int Th = T / 2;          // half fused with each inversion; Th/4 blocks

  // ---- merged prep: patchnorm + Zt/znorm/out-init + Kuu tiles ----
  k_prep<<<PNB_ + P1B_ + 288, 512, 0, stream>>>(
      xin, Z, vptr, lptr, Zt, znorm, outp, pat, pnorm, Kuu64, Kuu32);

  // ---- fp32 seed: Kinv32 via 2x2 block Schur (192+192); inversions fused
  //      with chunk-0 Kuf tiles (independent work on otherwise-idle CUs) ----
  k_invkufg<<<G_ + Th / 4, 1024, 0, stream>>>(
      Kuu32, Kinv32, pat, Zt, znorm, pnorm, vptr, lptr,
      Kx, Khi, Klo, 0, chx, 0);
  k_sgemm<<<dim3(6, 6, G_), 512, 0, stream>>>(
      Kinv32, M_, 0, MM_, Kuu32 + 192, M_, 0, 0, MM_,
      nullptr, 0, 0.0f, 1.0f, 0,
      Ebuf, 192, 192 * 192, nullptr, 0, 0, nullptr, nullptr, 192, 192, 192);
  k_sgemm<<<dim3(6, 6, G_), 512, 0, stream>>>(
      Kuu32 + 192, M_, 1, MM_, Ebuf, 192, 0, 0, 192 * 192,
      Kuu32 + 192 * M_ + 192, MM_, 1.0f, -1.0f, 0,
      Kuu32 + 192 * M_ + 192, M_, MM_, nullptr, 0, 0, nullptr, nullptr, 192, 192, 192);
  k_invkufg<<<G_ + Th / 4, 1024, 0, stream>>>(
      Kuu32 + 192 * M_ + 192, Kinv32 + 192 * M_ + 192, pat, Zt, znorm, pnorm,
      vptr, lptr, Kx, Khi, Klo, 0, chx, Th);
  k_sgemm<<<dim3(6, 6, G_), 512, 0, stream>>>(
      Ebuf, 192, 0, 192 * 192, Kinv32 + 192 * M_ + 192, M_, 0, 0, MM_,
      nullptr, 0, 0.0f, -1.0f, 0,
      Kinv32 + 192, M_, MM_, Kinv32 + 192 * M_, M_, MM_, nullptr, nullptr, 192, 192, 192);
  k_sgemm<<<dim3(6, 6, G_), 512, 0, stream>>>(
      Kinv32 + 192, M_, 0, MM_, Ebuf, 192, 1, 0, 192 * 192,
      Kinv32, MM_, 1.0f, -1.0f, 0,
      Kinv32, M_, MM_, nullptr, 0, 0, nullptr, nullptr, 192, 192, 192);

  // ---- Newton residual in fp64 (the only cancellation-critical GEMM):
  //      R = I - Kuu64*X0, output fp32 ----
  k_dgemmx<<<dim3(12, 12, G_), 512, 0, stream>>>(
      Kuu64, 1, M_, 0, (size_t)MM_,
      Kinv32, 0, M_, 0, 0, (size_t)MM_,
      nullptr, 0, 0, 0.0,
      -1.0, 1, nullptr, M_, (size_t)MM_, Rf, nullptr, nullptr, M_, M_, M_);
  // ---- X2 = X0 + X0*R : fp32 ----
  k_sgemm<<<dim3(12, 12, G_), 512, 0, stream>>>(
      Kinv32, M_, 0, MM_, Rf, M_, 0, 0, MM_,
      Kinv32, MM_, 1.0f, 1.0f, 0,
      Xf, M_, MM_, nullptr, 0, 0, nullptr, nullptr, M_, M_, M_);

  // ---- V = X2 * tril(Lq) : fp32 with exact-zero k-tile skip ----
  k_sgemm<<<dim3(12, 12, G_), 512, 0, stream>>>(
      Xf, M_, 0, MM_, qsqrt, M_, 0, 1, MM_,
      nullptr, 0, 0.0f, 1.0f, 0,
      Rf, M_, MM_, nullptr, 0, 0, nullptr, nullptr, M_, M_, M_);       // Rf = V
  // ---- S = V*V^T - X2 -> bf16 hi/lo; symmetric: lower tiles + mirror ----
  k_sgemm<<<dim3(12, 12, G_), 512, 0, stream>>>(
      Rf, M_, 0, MM_, Rf, M_, 1, 0, MM_,
      Xf, MM_, -1.0f, 1.0f, 0,
      nullptr, M_, MM_, nullptr, 0, 0, Shi, Slo, M_, M_, M_);
  k_cvec32<<<(G_ * M_ + 255) / 256, 256, 0, stream>>>(Xf, qmu, cvec);

  // ---- per-chunk: chunk 0's K already built by the fused kernels ----
  for (int ch = 0; ch < nc; ++ch) {
    int x0 = ch * chx;
    if (ch > 0)
      k_kufg<<<dim3(M_ / 64, chx / 64, G_), 256, 0, stream>>>(
          pat, Zt, znorm, pnorm, vptr, lptr, Kx, Khi, Klo, x0, chx);
    k_ufoldm<<<dim3(M_ / 128, chx / 128, G_), 256, 0, stream>>>(
        Khi, Klo, Kx, Shi, Slo, cvec, outp, x0, chx);
  }
}